// Round 23
// baseline (690.328 us; speedup 1.0000x reference)
//
#include <hip/hip_runtime.h>

// Problem constants (Bert4KGModel): B=4, T=S=512, D=1024, H=16, dh=64, F=4096, L=2
#define BB  4
#define TT  512
#define DD  1024
#define HH  16
#define DHH 64
#define FF  4096

typedef unsigned short u16;
typedef __attribute__((ext_vector_type(8))) short bfrag8;   // 8 bf16 (4 VGPRs)
typedef __attribute__((ext_vector_type(4))) float facc4;    // 4 f32 acc

__device__ __forceinline__ u16 f2bf(float f){
  unsigned u = __float_as_uint(f);
  unsigned r = u + 0x7fffu + ((u >> 16) & 1u);   // RNE
  return (u16)(r >> 16);
}
__device__ __forceinline__ float bf2f(u16 h){
  return __uint_as_float(((unsigned)h) << 16);
}

// async global->LDS, 16B per lane; LDS dest is wave-uniform base + lane*16
__device__ __forceinline__ void gload16(const u16* g, u16* l){
  __builtin_amdgcn_global_load_lds(
      (const __attribute__((address_space(1))) void*)g,
      (__attribute__((address_space(3))) void*)l, 16, 0, 0);
}

// counted vmcnt wait (literal immediates only) — used by flash
template<int N> __device__ __forceinline__ void vwait(){
  static_assert(N==0 || N==4, "bad vmcnt literal");
  if constexpr (N==0)  asm volatile("s_waitcnt vmcnt(0)" ::: "memory");
  else if constexpr (N==4)  asm volatile("s_waitcnt vmcnt(4)" ::: "memory");
}

// ---------------------------------------------------------------------------
// ONE prep launch (64x64 tiles, full-128B-line packed stores) + kv converts
// + fused embed+LN tail blocks. Transpose-range XCD swizzle (neutral-to-
// slightly-positive, kept).
// Blocks [0,14336): transposes. [14336,22528): converts. [22528,24576): embed.
// ---------------------------------------------------------------------------
__global__ __launch_bounds__(256) void prep_all(
    const float* __restrict__ Wq, const float* __restrict__ Wk,
    const float* __restrict__ Wv, const float* __restrict__ Wo,
    const float* __restrict__ W1, const float* __restrict__ W2,
    const float* __restrict__ g_db, const float* __restrict__ g_con,
    const float* __restrict__ g_usr, const float* __restrict__ g_enc,
    u16* __restrict__ dst0,
    u16* __restrict__ kvb0, u16* __restrict__ kvb1,
    u16* __restrict__ kvb2, u16* __restrict__ kvb3,
    const float* __restrict__ emb, const int* __restrict__ pvec,
    const float* __restrict__ pos, u16* __restrict__ xbout)
{
  const int fid = blockIdx.x;
  const int bid = (fid < 14336) ? ((fid & 7) * 1792 + (fid >> 3)) : fid;
  const int tid = threadIdx.x;
  if (bid >= 22528){                       // ---- fused embed + LN ----
    const int row = bid - 22528;
    const int lane = tid & 63, wid = tid >> 6;
    const int idx = pvec[row];
    const int t = row & (TT - 1);
    float4 e = ((const float4*)(emb + (long)idx * DD))[tid];
    float4 p = ((const float4*)(pos + (long)t * DD))[tid];
    float4 x;
    x.x = e.x * 32.0f + p.x; x.y = e.y * 32.0f + p.y;
    x.z = e.z * 32.0f + p.z; x.w = e.w * 32.0f + p.w;
    float s = x.x + x.y + x.z + x.w;
    #pragma unroll
    for (int o = 32; o; o >>= 1) s += __shfl_xor(s, o);
    __shared__ float red[4];
    if (lane == 0) red[wid] = s;
    __syncthreads();
    const float mean = (red[0] + red[1] + red[2] + red[3]) * (1.0f / DD);
    __syncthreads();
    const float dx = x.x - mean, dy = x.y - mean, dz = x.z - mean, dw = x.w - mean;
    float q = dx*dx + dy*dy + dz*dz + dw*dw;
    #pragma unroll
    for (int o = 32; o; o >>= 1) q += __shfl_xor(q, o);
    if (lane == 0) red[wid] = q;
    __syncthreads();
    const float var = (red[0] + red[1] + red[2] + red[3]) * (1.0f / DD);
    const float rstd = rsqrtf(var + 1e-5f);
    ushort4 o4;
    o4.x = f2bf(dx*rstd); o4.y = f2bf(dy*rstd);
    o4.z = f2bf(dz*rstd); o4.w = f2bf(dw*rstd);
    ((ushort4*)(xbout + (long)row * DD))[tid] = o4;
    return;
  }
  if (bid >= 14336){                       // ---- kv convert ----
    const int r = bid - 14336;
    const float* s; u16* d;
    switch (r >> 11){
      case 0: s = g_db;  d = kvb0; break;
      case 1: s = g_con; d = kvb1; break;
      case 2: s = g_usr; d = kvb2; break;
      default: s = g_enc; d = kvb3; break;
    }
    const int i = (r & 2047) * 256 + tid;
    float4 v = ((const float4*)s)[i];
    ushort4 o;
    o.x = f2bf(v.x); o.y = f2bf(v.y); o.z = f2bf(v.z); o.w = f2bf(v.w);
    ((ushort4*)d)[i] = o;
    return;
  }
  constexpr long D2 = (long)DD * DD, DF = (long)DD * FF;
  constexpr long O_Wproj = 0, O_WkvC = 14*D2, O_WoT = 30*D2,
                 O_W1T = 40*D2, O_W2T = 40*D2 + 2*DF;
  const float* src; long soff, doff; int R, C, rem;
  if (bid < 1536){                         // self Wq/Wk/Wv (j) x layer (l)
    const int j = bid / 512;
    src = (j==0) ? Wq : (j==1) ? Wk : Wv;
    const int l = (bid % 512) / 256; rem = bid & 255;
    soff = (long)l * 5 * D2;
    doff = O_Wproj + (long)l * 7 * D2 +
           ((j==0) ? 0L : (j==1) ? 5L*D2 : 6L*D2);
    R = DD; C = DD;
  } else if (bid < 5632){                  // cross K/V: (l, ci, kv)
    const int idx = (bid - 1536) >> 8; rem = bid & 255;
    const int l = idx >> 3, ci = (idx >> 1) & 3, kv = idx & 1;
    src = kv ? Wv : Wk;
    soff = (long)(l*5 + 1 + ci) * D2;
    doff = O_WkvC + (long)(l*8 + ci*2 + kv) * D2;
    R = DD; C = DD;
  } else if (bid < 7680){                  // cross Q: (l, ci) -> slot 1+ci
    const int idx = (bid - 5632) >> 8; rem = bid & 255;
    const int l = idx >> 2, ci = idx & 3;
    src = Wq;
    soff = (long)(l*5 + 1 + ci) * D2;
    doff = O_Wproj + (long)l * 7 * D2 + (long)(1 + ci) * D2;
    R = DD; C = DD;
  } else if (bid < 10240){                 // Wo (10 matrices)
    const int idx = (bid - 7680) >> 8; rem = bid & 255;
    src = Wo; soff = (long)idx * D2; doff = O_WoT + (long)idx * D2;
    R = DD; C = DD;
  } else if (bid < 12288){                 // W1 [DD][FF], z=2
    const int b5 = bid - 10240;
    const int z = b5 >> 10; rem = b5 & 1023;
    src = W1; soff = (long)z * DF; doff = O_W1T + (long)z * DF;
    R = DD; C = FF;
  } else {                                 // W2 [FF][DD], z=2
    const int b6 = bid - 12288;
    const int z = b6 >> 10; rem = b6 & 1023;
    src = W2; soff = (long)z * DF; doff = O_W2T + (long)z * DF;
    R = FF; C = DD;
  }
  const int ctiles = C >> 6;
  const int c0 = (rem % ctiles) << 6;
  const int r0 = (rem / ctiles) << 6;

  __shared__ u16 tile[64][66];
  const int tr = tid >> 4, tc = tid & 15;
  #pragma unroll
  for (int i = 0; i < 4; ++i){
    const int row = tr + i*16;
    float4 v = ((const float4*)(src + soff + (long)(r0 + row)*C + c0))[tc];
    unsigned* t32 = (unsigned*)&tile[row][tc*4];
    t32[0] = (unsigned)f2bf(v.x) | ((unsigned)f2bf(v.y) << 16);
    t32[1] = (unsigned)f2bf(v.z) | ((unsigned)f2bf(v.w) << 16);
  }
  __syncthreads();
  const int ch = tid & 7;
  const int cb = tid >> 3;                 // 0..31
  #pragma unroll
  for (int it = 0; it < 2; ++it){
    const int cc = cb + it*32;             // output row = source col
    union { int4 v; u16 u[8]; } P;
    #pragma unroll
    for (int j = 0; j < 8; ++j) P.u[j] = tile[ch*8 + j][cc];
    *(int4*)&dst0[doff + (long)(c0 + cc)*R + r0 + ch*8] = P.v;
  }
}

// ---------------------------------------------------------------------------
// Chained residual+LN: x = LN(...LN(LN(x + o0) + o1)... + o4), f32 registers.
// ---------------------------------------------------------------------------
__global__ __launch_bounds__(256) void ln_chain5(
    const float* __restrict__ o5, u16* __restrict__ xb)
{
  const int row = blockIdx.x;
  const int i = threadIdx.x;
  const int lane = i & 63, wid = i >> 6;
  __shared__ float red[4];
  constexpr long NB = (long)2048 * 1024;
  ushort4 x4 = ((const ushort4*)(xb + (long)row * DD))[i];
  float4 x;
  x.x = bf2f(x4.x); x.y = bf2f(x4.y); x.z = bf2f(x4.z); x.w = bf2f(x4.w);
  #pragma unroll
  for (int it = 0; it < 5; ++it){
    float4 o = ((const float4*)(o5 + (long)it * NB + (long)row * DD))[i];
    x.x += o.x; x.y += o.y; x.z += o.z; x.w += o.w;
    float s = x.x + x.y + x.z + x.w;
    #pragma unroll
    for (int off = 32; off; off >>= 1) s += __shfl_xor(s, off);
    if (lane == 0) red[wid] = s;
    __syncthreads();
    const float mean = (red[0] + red[1] + red[2] + red[3]) * (1.0f / DD);
    __syncthreads();
    x.x -= mean; x.y -= mean; x.z -= mean; x.w -= mean;
    float q = x.x*x.x + x.y*x.y + x.z*x.z + x.w*x.w;
    #pragma unroll
    for (int off = 32; off; off >>= 1) q += __shfl_xor(q, off);
    if (lane == 0) red[wid] = q;
    __syncthreads();
    const float var = (red[0] + red[1] + red[2] + red[3]) * (1.0f / DD);
    const float rstd = rsqrtf(var + 1e-5f);
    x.x *= rstd; x.y *= rstd; x.z *= rstd; x.w *= rstd;
    __syncthreads();
  }
  ushort4 o4;
  o4.x = f2bf(x.x); o4.y = f2bf(x.y); o4.z = f2bf(x.z); o4.w = f2bf(x.w);
  ((ushort4*)(xb + (long)row * DD))[i] = o4;
}

// ---------------------------------------------------------------------------
// LayerNorm(a) -> yf (f32, optional) and yb (bf16, optional)
// ---------------------------------------------------------------------------
__global__ __launch_bounds__(256) void ln_kernel(
    const float* __restrict__ a,
    float* __restrict__ yf, u16* __restrict__ yb)
{
  const int row = blockIdx.x;
  const int i = threadIdx.x;
  const int lane = i & 63, wid = i >> 6;
  float4 x = ((const float4*)(a + (long)row * DD))[i];
  float s = x.x + x.y + x.z + x.w;
  #pragma unroll
  for (int o = 32; o; o >>= 1) s += __shfl_xor(s, o);
  __shared__ float red[4];
  if (lane == 0) red[wid] = s;
  __syncthreads();
  const float mean = (red[0] + red[1] + red[2] + red[3]) * (1.0f / DD);
  __syncthreads();
  const float dx = x.x - mean, dy = x.y - mean, dz = x.z - mean, dw = x.w - mean;
  float q = dx*dx + dy*dy + dz*dz + dw*dw;
  #pragma unroll
  for (int o = 32; o; o >>= 1) q += __shfl_xor(q, o);
  if (lane == 0) red[wid] = q;
  __syncthreads();
  const float var = (red[0] + red[1] + red[2] + red[3]) * (1.0f / DD);
  const float rstd = rsqrtf(var + 1e-5f);
  float4 y; y.x = dx*rstd; y.y = dy*rstd; y.z = dz*rstd; y.w = dw*rstd;
  if (yf) ((float4*)(yf + (long)row * DD))[i] = y;
  if (yb){
    ushort4 o4; o4.x = f2bf(y.x); o4.y = f2bf(y.y); o4.z = f2bf(y.z); o4.w = f2bf(y.w);
    ((ushort4*)(yb + (long)row * DD))[i] = o4;
  }
}

// ---------------------------------------------------------------------------
// Flash attention core (shared).
// ---------------------------------------------------------------------------
template<bool CAUSAL>
__device__ __forceinline__ void flash_body(
    const u16* Q, const u16* Kt, const u16* Vt,
    const float* biasS, u16* O,
    int qt, int bh, u16 (*Ks)[64*64], u16 (*Vs)[64*64], u16* Ps)
{
  const int b = bh >> 4, h = bh & 15;
  const int tid = threadIdx.x, lane = tid & 63, wid = tid >> 6;
  const int fr = lane & 15, kg = lane >> 4;
  const int srow = tid >> 3;
  const int gcol = ((tid & 7) ^ (srow & 7)) * 8;
  u16* Pw = Ps + wid * 1024;
  const facc4 z4 = {0.0f, 0.0f, 0.0f, 0.0f};

  const long base = (long)bh * (512 * 64);
  const u16* qrow = Q + base + (long)(qt*64 + wid*16 + fr) * 64;
  const bfrag8 aq0 = *(const bfrag8*)(qrow + kg*8);
  const bfrag8 aq1 = *(const bfrag8*)(qrow + 32 + kg*8);

  auto stageKV = [&](int buf, int kt){
    u16* Kd = Ks[buf] + wid * 512;
    u16* Vd = Vs[buf] + wid * 512;
    #pragma unroll
    for (int p = 0; p < 2; ++p)
      gload16(Kt + base + (long)(kt*64 + p*32 + srow) * 64 + gcol, Kd + p*2048);
    #pragma unroll
    for (int p = 0; p < 2; ++p)
      gload16(Vt + base + (long)(p*32 + srow) * 512 + kt*64 + gcol, Vd + p*2048);
  };

  float mrow[4], lrow[4];
  #pragma unroll
  for (int r = 0; r < 4; ++r){ mrow[r] = -3e38f; lrow[r] = 0.0f; }
  facc4 accO[4] = {};

  const int NT = CAUSAL ? (qt + 1) : 8;
  stageKV(0, 0);
  if (NT > 1){ stageKV(1, 1); vwait<4>(); }
  else vwait<0>();
  __builtin_amdgcn_s_barrier();

  for (int kt = 0; kt < NT; ++kt){
    const int cur = kt & 1;
    bfrag8 bk[4][2], bv[4][2];
    #pragma unroll
    for (int j = 0; j < 4; ++j)
      #pragma unroll
      for (int c2 = 0; c2 < 2; ++c2){
        const int po = (((c2*4 + kg) ^ (fr & 7)) * 8);
        bk[j][c2] = *(const bfrag8*)&Ks[cur][(j*16 + fr)*64 + po];
        bv[j][c2] = *(const bfrag8*)&Vs[cur][(j*16 + fr)*64 + po];
      }
    __builtin_amdgcn_sched_barrier(0);
    __builtin_amdgcn_s_barrier();
    if (kt + 2 < NT){ stageKV(cur, kt + 2); vwait<4>(); }
    else vwait<0>();
    __builtin_amdgcn_s_barrier();

    // QK^T
    facc4 sc[4];
    __builtin_amdgcn_s_setprio(1);
    #pragma unroll
    for (int j = 0; j < 4; ++j){
      sc[j] = __builtin_amdgcn_mfma_f32_16x16x32_bf16(aq0, bk[j][0], z4, 0, 0, 0);
      sc[j] = __builtin_amdgcn_mfma_f32_16x16x32_bf16(aq1, bk[j][1], sc[j], 0, 0, 0);
    }
    __builtin_amdgcn_s_setprio(0);
    if (CAUSAL){
      const int rowb = qt*64 + wid*16 + kg*4;
      #pragma unroll
      for (int j = 0; j < 4; ++j){
        const int col = kt*64 + j*16 + fr;
        #pragma unroll
        for (int r = 0; r < 4; ++r)
          if (col > rowb + r) sc[j][r] = -1e20f;
      }
    } else {
      #pragma unroll
      for (int j = 0; j < 4; ++j){
        const float bval = biasS[kt*64 + j*16 + fr];
        #pragma unroll
        for (int r = 0; r < 4; ++r) sc[j][r] += bval;
      }
    }
    // online softmax
    float tmax[4];
    #pragma unroll
    for (int r = 0; r < 4; ++r)
      tmax[r] = fmaxf(fmaxf(sc[0][r], sc[1][r]), fmaxf(sc[2][r], sc[3][r]));
    #pragma unroll
    for (int o = 1; o < 16; o <<= 1)
      #pragma unroll
      for (int r = 0; r < 4; ++r)
        tmax[r] = fmaxf(tmax[r], __shfl_xor(tmax[r], o));
    float fac[4];
    #pragma unroll
    for (int r = 0; r < 4; ++r){
      const float mn = fmaxf(mrow[r], tmax[r]);
      fac[r] = __expf(mrow[r] - mn);
      mrow[r] = mn;
    }
    float tsum[4] = {0.0f, 0.0f, 0.0f, 0.0f};
    #pragma unroll
    for (int j = 0; j < 4; ++j)
      #pragma unroll
      for (int r = 0; r < 4; ++r){
        const float p = __expf(sc[j][r] - mrow[r]);
        sc[j][r] = p; tsum[r] += p;
      }
    #pragma unroll
    for (int o = 1; o < 16; o <<= 1)
      #pragma unroll
      for (int r = 0; r < 4; ++r) tsum[r] += __shfl_xor(tsum[r], o);
    #pragma unroll
    for (int r = 0; r < 4; ++r) lrow[r] = lrow[r]*fac[r] + tsum[r];
    #pragma unroll
    for (int f = 0; f < 4; ++f)
      #pragma unroll
      for (int r = 0; r < 4; ++r) accO[f][r] *= fac[r];

    // P -> wave-private LDS (chunk-swizzled), read back as A-frags
    #pragma unroll
    for (int j = 0; j < 4; ++j)
      #pragma unroll
      for (int r = 0; r < 4; ++r){
        const int row = kg*4 + r;
        const int col = j*16 + fr;
        Pw[row*64 + (((col >> 3) ^ (row & 7)) * 8) + (col & 7)] = f2bf(sc[j][r]);
      }
    bfrag8 ap[2];
    #pragma unroll
    for (int c2 = 0; c2 < 2; ++c2)
      ap[c2] = *(const bfrag8*)&Pw[fr*64 + (((c2*4 + kg) ^ (fr & 7)) * 8)];
    __builtin_amdgcn_s_setprio(1);
    #pragma unroll
    for (int f = 0; f < 4; ++f){
      accO[f] = __builtin_amdgcn_mfma_f32_16x16x32_bf16(ap[0], bv[f][0], accO[f], 0, 0, 0);
      accO[f] = __builtin_amdgcn_mfma_f32_16x16x32_bf16(ap[1], bv[f][1], accO[f], 0, 0, 0);
    }
    __builtin_amdgcn_s_setprio(0);
  }

  // epilogue: O/lrow via Pw bounce -> coalesced 16B stores
  #pragma unroll
  for (int f = 0; f < 4; ++f)
    #pragma unroll
    for (int r = 0; r < 4; ++r){
      const int row = kg*4 + r;
      const int col = f*16 + fr;
      Pw[(row*64 + col) ^ ((row & 7) << 3)] = f2bf(accO[f][r] / lrow[r]);
    }
  const int prow = lane >> 2, pch = lane & 3;
  const long orow = (long)(b*512 + qt*64 + wid*16 + prow) * 1024 + h*64;
  #pragma unroll
  for (int it2 = 0; it2 < 2; ++it2){
    const int ch2 = pch + it2*4;
    int4 w4 = *(const int4*)&Pw[(prow*64 + ch2*8) ^ ((prow & 7) << 3)];
    *(int4*)&O[orow + ch2*8] = w4;
  }
}

// ---- ALL 5 attentions in one launch, grid (8,64,5); z=0 self, z>=1 cross ----
__global__ __launch_bounds__(256, 3) void flash_all5(
    const u16* __restrict__ Qb5, const u16* __restrict__ Kb,
    const u16* __restrict__ Vtb, const u16* __restrict__ KVcl,
    const int* __restrict__ cmask, u16* __restrict__ O5)
{
  __shared__ __align__(16) u16 Ks[2][64*64];
  __shared__ __align__(16) u16 Vs[2][64*64];
  __shared__ __align__(16) u16 Ps[4*16*64];
  __shared__ float biasS[512];
  const int z = blockIdx.z;
  const int fid = blockIdx.y * 8 + blockIdx.x;
  const int lid = (fid & 7) * 64 + (fid >> 3);
  const int qt = lid & 7, bh = lid >> 3;
  constexpr long NB = (long)2048 * 1024;
  if (z == 0){
    flash_body<true>(Qb5, Kb, Vtb, nullptr, O5, qt, bh, Ks, Vs, Ps);
  } else {
    const int ci = z - 1;
    const int mode = (0x0312 >> (ci*4)) & 0xF;   // ci: 0->2, 1->1, 2->3, 3->0
    const int b = bh >> 4;
    const int tid = threadIdx.x;
    #pragma unroll
    for (int r = 0; r < 2; ++r){
      const int c = r * 256 + tid;
      biasS[c] = (cmask[b * 512 + c] != mode) ? 0.0f : -1e20f;
    }
    __syncthreads();
    flash_body<false>(Qb5 + (long)z * NB,
                      KVcl + (long)(ci*2) * NB, KVcl + (long)(ci*2 + 1) * NB,
                      biasS, O5 + (long)z * NB, qt, bh, Ks, Vs, Ps);
  }
}

// ---------------------------------------------------------------------------
#define MODE_F32   0
#define MODE_BF16  1
#define MODE_KV    4
#define MODE_PROJ  6
#define MODE_F32B  7

__device__ __forceinline__ long qk_off(int gm, int gn){   // [b,h,t,d]
  return (((long)(gm >> 9) * HH + (gn >> 6)) * TT + (gm & (TT-1))) * DHH + (gn & (DHH-1));
}

// ---------------------------------------------------------------------------
// m97-structure bf16 MFMA GEMM: BK=32, SINGLE LDS buffer (16-32KB), plain
// 2-barrier loop, ~3 blocks/CU — latency hiding via inter-block TLP (m114).
// 4-chunk XOR swizzle (r2 PMC-verified: 0 bank conflicts).
// LDS = max(staging, epilogue bounce).
// ---------------------------------------------------------------------------
template<int BM, int BN, int MODE>
__global__ __launch_bounds__(256, 3) void gemm_k(
    const u16* __restrict__ A, const u16* __restrict__ B,
    const float* __restrict__ bias0, const float* __restrict__ bias1,
    const float* __restrict__ bias2,
    float* __restrict__ Cf, u16* __restrict__ Cb0, u16* __restrict__ Cb1,
    u16* __restrict__ Cb2, const u16* __restrict__ resb,
    int K, int lda, int ldb, int ldc,
    int relu, float alpha)
{
  constexpr int BK = 32;
  constexpr int ASZ = BM * BK, BSZ = BN * BK;           // u16
  constexpr int BOUNCE = BM * BN;
  constexpr int LDSTOT = (ASZ + BSZ > BOUNCE) ? (ASZ + BSZ) : BOUNCE;
  __shared__ __align__(16) u16 lds[LDSTOT];
  u16* As = lds;
  u16* Bs = lds + ASZ;

  const int gx = gridDim.x, gy = gridDim.y;
  const int nwg = gx * gy * gridDim.z;
  const int fid = (blockIdx.z * gy + blockIdx.y) * gx + blockIdx.x;
  const int cpx = nwg >> 3;
  const int lid = (fid & 7) * cpx + (fid >> 3);
  const int bx = lid % gx;
  const int rem = lid / gx;
  const int by = rem % gy;
  const int z  = rem / gy;

  const u16* Ab;
  const u16* Bb;
  long cbase;
  constexpr long NBA = (long)2048 * 1024;
  constexpr long D2C = (long)DD * DD;
  if constexpr (MODE == MODE_KV){
    const int ci = z >> 2, ll = (z >> 1) & 1, isv = z & 1;
    Ab = A + (long)ci * NBA;
    Bb = B + (long)(ll*8 + ci*2 + isv) * D2C;
    cbase = (long)(ll*8 + ci*2 + isv) * NBA;
  } else if constexpr (MODE == MODE_F32B){
    Ab = A + (long)z * NBA;
    Bb = B + (long)z * D2C;
    cbase = (long)z * NBA;
  } else {
    Ab = A; Bb = B; cbase = 0;
  }
  const int tid = threadIdx.x, lane = tid & 63, wid = tid >> 6;
  const int m0 = by * BM, n0 = bx * BN;
  constexpr int TMW = BM / 2, TNW = BN / 2;           // 2x2 wave grid
  constexpr int FM = TMW / 16, FN = TNW / 16;
  const int wm = (wid >> 1) * TMW, wn = (wid & 1) * TNW;
  const int fr = lane & 15, kg = lane >> 4;
  facc4 acc[FM][FN] = {};

  // staging: pass = 64 rows of 64B (4KB); thread t -> row t>>2, phys chunk t&3
  // global chunk pre-swizzled: LDS[r][c] = G[r][c ^ ((r>>1)&3)]
  const int srow = tid >> 2;
  const int gcol = (((tid & 3) ^ ((srow >> 1) & 3)) * 8);
  constexpr int AP = BM / 64, BP = BN / 64;
  const int rsw = (kg ^ ((fr >> 1) & 3)) * 8;        // read-side swizzled chunk

  const int nsteps = K / BK;
  for (int s = 0; s < nsteps; ++s){
    const int k0 = s * BK;
    #pragma unroll
    for (int p = 0; p < AP; ++p)
      gload16(Ab + (long)(m0 + p*64 + srow) * lda + (k0 + gcol),
              As + wid*512 + p*2048);
    #pragma unroll
    for (int p = 0; p < BP; ++p)
      gload16(Bb + (long)(n0 + p*64 + srow) * ldb + (k0 + gcol),
              Bs + wid*512 + p*2048);
    __syncthreads();                       // drains vmcnt -> tile visible
    bfrag8 af[FM], bfv[FN];
    #pragma unroll
    for (int i = 0; i < FM; ++i)
      af[i] = *(const bfrag8*)&As[(wm + i*16 + fr) * 32 + rsw];
    #pragma unroll
    for (int j = 0; j < FN; ++j)
      bfv[j] = *(const bfrag8*)&Bs[(wn + j*16 + fr) * 32 + rsw];
    #pragma unroll
    for (int i = 0; i < FM; ++i)
      #pragma unroll
      for (int j = 0; j < FN; ++j)
        acc[i][j] = __builtin_amdgcn_mfma_f32_16x16x32_bf16(af[i], bfv[j], acc[i][j], 0, 0, 0);
    __syncthreads();                       // LDS reads done before next stage
  }

  // ---- V^T output path: LDS transpose bounce -> coalesced stores ----
  if constexpr (MODE == MODE_KV || MODE == MODE_PROJ){
    const float* vb = nullptr; u16* vdst = nullptr; int n0e = 0; bool vpath = false;
    if constexpr (MODE == MODE_KV){
      const int ci = z >> 2, ll = (z >> 1) & 1, isv = z & 1;
      if (isv){ vpath = true; vb = bias1 + (long)(ll*5 + ci + 1) * DD; vdst = Cb0 + cbase; n0e = n0; }
    } else {
      if ((n0 >> 10) == 6){ vpath = true; vb = bias2; vdst = Cb2; n0e = n0 - 6144; }
    }
    if (vpath){
      u16* S = lds;
      #pragma unroll
      for (int j = 0; j < FN; ++j){
        const int nl = wn + j*16 + fr;
        const float bvv = vb[n0e + nl];
        #pragma unroll
        for (int i = 0; i < FM; ++i)
          #pragma unroll
          for (int rr = 0; rr < 4; ++rr){
            const int ml = wm + i*16 + kg*4 + rr;
            S[(nl*BM + ml) ^ ((nl & 7) << 3)] = f2bf(acc[i][j][rr] + bvv);
          }
      }
      __syncthreads();
      constexpr int TPR = 256 / BN;
      constexpr int CPT = BM / (8 * TPR);
      const int n = tid / TPR;
      const int mh = (tid % TPR) * (BM / TPR);
      const long rowoff = (((long)(m0 >> 9) * HH + ((n0e + n) >> 6)) * DHH
                           + ((n0e + n) & 63)) * TT + (m0 & 511) + mh;
      #pragma unroll
      for (int c = 0; c < CPT; ++c){
        int4 w4 = *(const int4*)&S[(n*BM + mh + c*8) ^ ((n & 7) << 3)];
        *(int4*)&vdst[rowoff + c*8] = w4;
      }
      return;
    }
  }

  // ---- bf16 row-major bounce (MODE_BF16 / PROJ Q,K / KV K-side) ----
  if constexpr (MODE == MODE_BF16 || MODE == MODE_PROJ || MODE == MODE_KV){
    u16* S = lds;                // LDSTOT >= BM*BN u16 for all configs
    const float* bp = bias0;
    float sc2 = alpha;
    u16* dst = Cb0;
    int nb = 0;
    constexpr long NBA2 = (long)2048 * 1024;
    if constexpr (MODE == MODE_KV){
      const int ci = z >> 2, ll = (z >> 1) & 1;
      bp = bias0 + (long)(ll*5 + ci + 1) * DD;
    } else if constexpr (MODE == MODE_PROJ){
      const int sect = n0 >> 10;           // 0..5 here (128 | 1024 -> no straddle)
      nb = n0 & 1023;
      if (sect <= 4){ bp = bias0 + (long)sect * DD; sc2 = 0.125f; dst = Cb0 + (long)sect * NBA2; }
      else          { bp = bias1; sc2 = 1.0f; dst = Cb1; }
    }
    #pragma unroll
    for (int i = 0; i < FM; ++i)
      #pragma unroll
      for (int j = 0; j < FN; ++j){
        const int nl = wn + j*16 + fr;
        float bvv;
        if constexpr (MODE == MODE_PROJ) bvv = bp[nb + nl];
        else bvv = bp ? bp[n0 + nl] : 0.0f;
        #pragma unroll
        for (int rr = 0; rr < 4; ++rr){
          const int ml = wm + i*16 + kg*4 + rr;
          float v = (acc[i][j][rr] + bvv) * sc2;
          if (relu) v = fmaxf(v, 0.0f);
          S[(ml*BN + nl) ^ ((ml & 7) << 3)] = f2bf(v);
        }
      }
    __syncthreads();
    constexpr int CPR = BN / 8;                 // 16B chunks per row
    constexpr int NIT = (BM * CPR) / 256;
    #pragma unroll
    for (int it = 0; it < NIT; ++it){
      const int idx = it * 256 + tid;
      const int row = idx / CPR, ch = idx % CPR;
      int4 w4 = *(const int4*)&S[(row*BN + ch*8) ^ ((row & 7) << 3)];
      const int gm = m0 + row;
      long off;
      if constexpr (MODE == MODE_BF16) off = cbase + (long)gm * ldc + (n0 + ch*8);
      else if constexpr (MODE == MODE_PROJ) off = qk_off(gm, nb + ch*8);
      else off = cbase + qk_off(gm, n0 + ch*8);
      *(int4*)&dst[off] = w4;
    }
    return;
  }

  // Epilogue (MODE_F32 / MODE_F32B). C/D layout: col = fr, row = kg*4 + rr.
  {
    const float* bp0 = bias0;
    if constexpr (MODE == MODE_F32B) bp0 = bias0 + (long)z * DD;
    #pragma unroll
    for (int i = 0; i < FM; ++i){
      #pragma unroll
      for (int j = 0; j < FN; ++j){
        const int gn = n0 + wn + j*16 + fr;
        #pragma unroll
        for (int rr = 0; rr < 4; ++rr){
          const int gm = m0 + wm + i*16 + kg*4 + rr;
          float v = acc[i][j][rr];
          v = (v + (bp0 ? bp0[gn] : 0.0f)) * alpha;
          if (relu) v = fmaxf(v, 0.0f);
          const long off = cbase + (long)gm * ldc + gn;
          if constexpr (MODE == MODE_F32){
            if (resb) v += bf2f(resb[off]);        // fused bf16 residual
          }
          Cf[off] = v;
        }
      }
    }
  }
}

// ---------------------------------------------------------------------------
extern "C" void kernel_launch(void* const* d_in, const int* in_sizes, int n_in,
                              void* d_out, int out_size, void* d_ws, size_t ws_size,
                              hipStream_t stream)
{
  (void)in_sizes; (void)n_in; (void)out_size; (void)ws_size;
  const float* emb   = (const float*)d_in[0];
  const int*   pvec  = (const int*)d_in[1];
  const float* g_enc = (const float*)d_in[2];
  const float* g_con = (const float*)d_in[3];
  const float* g_db  = (const float*)d_in[4];
  const float* g_usr = (const float*)d_in[5];
  const int*   cmask = (const int*)d_in[6];
  const float* pose  = (const float*)d_in[7];
  const float* Wq = (const float*)d_in[8];
  const float* bq = (const float*)d_in[9];
  const float* Wk = (const float*)d_in[10];
  const float* bk = (const float*)d_in[11];
  const float* Wv = (const float*)d_in[12];
  const float* bv = (const float*)d_in[13];
  const float* Wo = (const float*)d_in[14];
  const float* bo = (const float*)d_in[15];
  const float* W1 = (const float*)d_in[16];
  const float* b1 = (const float*)d_in[17];
  const float* W2 = (const float*)d_in[18];
  const float* b2 = (const float*)d_in[19];
  float* out = (float*)d_out;

  const size_t NTOK = (size_t)BB * TT;   // 2048
  const long D2 = (long)DD * DD;

  char* wp = (char*)d_ws;
  auto alloc = [&](size_t bytes) -> char* {
    char* p = wp;
    wp += (bytes + 255) & ~(size_t)255;
    return p;
  };
  // NOTE: the first 5 arrays' order/offsets are hard-coded in prep_all.
  u16*   WprojT = (u16*) alloc(sizeof(u16) * 2 * 7 * D2);   // [l][7 slots]
  u16*   WkvC   = (u16*) alloc(sizeof(u16) * 2 * 4 * 2 * D2);
  u16*   WoT    = (u16*) alloc(sizeof(u16) * 10 * D2);
  u16*   W1T    = (u16*) alloc(sizeof(u16) * 2 * DD * FF);
  u16*   W2T    = (u16*) alloc(sizeof(u16) * 2 * DD * FF);
  // kvb0..3 MUST stay contiguous: MODE_KV indexes them as [4][NTOK][DD]
  u16*   kvb0  = (u16*)  alloc(sizeof(u16) * NTOK * DD);
  u16*   kvb1  = (u16*)  alloc(sizeof(u16) * NTOK * DD);
  u16*   kvb2  = (u16*)  alloc(sizeof(u16) * NTOK * DD);
  u16*   kvb3  = (u16*)  alloc(sizeof(u16) * NTOK * DD);
  u16*   KVc   = (u16*)  alloc(sizeof(u16) * 16 * NTOK * DD);
  u16*   xb    = (u16*)  alloc(sizeof(u16) * NTOK * DD);
  u16*   Qb5   = (u16*)  alloc(sizeof(u16) * 5 * NTOK * DD);
  u16*   Kb    = (u16*)  alloc(sizeof(u16) * NTOK * DD);
  u16*   Vtb   = (u16*)  alloc(sizeof(u16) * NTOK * DD);
  u16*   attnb5= (u16*)  alloc(sizeof(u16) * 5 * NTOK * DD);
  float* oproj5= (float*)alloc(sizeof(float) * 5 * NTOK * DD);
  float* obuf  = (float*)alloc(sizeof(float) * NTOK * DD);
  u16*   hb    = (u16*)  alloc(sizeof(u16) * NTOK * FF);

  // ---- ONE prep launch: transposes + kv converts + embed/LN ----
  prep_all<<<24576, 256, 0, stream>>>(
      Wq, Wk, Wv, Wo, W1, W2, g_db, g_con, g_usr, g_enc,
      (u16*)d_ws, kvb0, kvb1, kvb2, kvb3,
      emb, pvec, pose, xb);

  // ---- all cross-attention K/V in ONE 2048-block launch (16 z-batches) ----
  const long NB = (long)NTOK * DD;
  gemm_k<128,128,MODE_KV><<<dim3(8,16,16), 256, 0, stream>>>(
    kvb0, WkvC, bk, bv, nullptr,
    nullptr, KVc, nullptr, nullptr, nullptr,
    DD, DD, DD, 0, 0, 1.0f);

  for (int l = 0; l < 2; ++l){
    // ---- batched projections: [Q x5 | K_self | V_self], N = 7168 ----
    gemm_k<128,128,MODE_PROJ><<<dim3(56,16,1), 256, 0, stream>>>(
      xb, WprojT + (long)l*7*D2,
      bq + (size_t)l*5*DD, bk + (size_t)l*5*DD, bv + (size_t)l*5*DD,
      nullptr, Qb5, Kb, Vtb, nullptr,
      DD, DD, DD, 0, 0, 1.0f);

    // ALL 5 attentions (self causal + 4 cross) in one launch
    flash_all5<<<dim3(8,64,5), 256, 0, stream>>>(
        Qb5, Kb, Vtb, KVc + (long)l*8*NB, cmask, attnb5);

    // ALL 5 O-projections batched (z = i), f32 out, 128x128 tiles
    gemm_k<128,128,MODE_F32B><<<dim3(8,16,5), 256, 0, stream>>>(
      attnb5, WoT + (long)l*5*D2,
      bo + (size_t)l*5*DD, nullptr, nullptr,
      oproj5, nullptr, nullptr, nullptr, nullptr,
      DD, DD, DD, DD, 0, 1.0f);

    // chained residual+LN (one launch, f32 registers across 5 steps)
    ln_chain5<<<(int)NTOK, 256, 0, stream>>>(oproj5, xb);

    // FFN
    gemm_k<128,128,MODE_BF16><<<dim3(32,16,1), 256, 0, stream>>>(
      xb, W1T + (size_t)l*DD*FF,
      b1 + (size_t)l*FF, nullptr, nullptr,
      nullptr, hb, nullptr, nullptr, nullptr,
      DD, DD, DD, FF, 1, 1.0f);
    gemm_k<64,64,MODE_F32><<<dim3(16,32,1), 256, 0, stream>>>(
      hb, W2T + (size_t)l*DD*FF,
      b2 + (size_t)l*DD, nullptr, nullptr,
      obuf, nullptr, nullptr, nullptr, xb,
      FF, FF, FF, DD, 0, 1.0f);
    float* yf = (l == 1) ? out : nullptr;
    ln_kernel<<<(int)NTOK, 256, 0, stream>>>(obuf, yf, (l == 1) ? nullptr : xb);
  }
}

// Round 24
// 675.418 us; speedup vs baseline: 1.0221x; 1.0221x over previous
//
#include <hip/hip_runtime.h>

// Problem constants (Bert4KGModel): B=4, T=S=512, D=1024, H=16, dh=64, F=4096, L=2
#define BB  4
#define TT  512
#define DD  1024
#define HH  16
#define DHH 64
#define FF  4096

typedef unsigned short u16;
typedef __attribute__((ext_vector_type(8))) short bfrag8;   // 8 bf16 (4 VGPRs)
typedef __attribute__((ext_vector_type(4))) float facc4;    // 4 f32 acc

__device__ __forceinline__ u16 f2bf(float f){
  unsigned u = __float_as_uint(f);
  unsigned r = u + 0x7fffu + ((u >> 16) & 1u);   // RNE
  return (u16)(r >> 16);
}
__device__ __forceinline__ float bf2f(u16 h){
  return __uint_as_float(((unsigned)h) << 16);
}

// async global->LDS, 16B per lane; LDS dest is wave-uniform base + lane*16
__device__ __forceinline__ void gload16(const u16* g, u16* l){
  __builtin_amdgcn_global_load_lds(
      (const __attribute__((address_space(1))) void*)g,
      (__attribute__((address_space(3))) void*)l, 16, 0, 0);
}

// counted vmcnt wait (literal immediates only)
template<int N> __device__ __forceinline__ void vwait(){
  static_assert(N==0 || N==4 || N==6 || N==8 || N==12, "bad vmcnt literal");
  if constexpr (N==0)  asm volatile("s_waitcnt vmcnt(0)" ::: "memory");
  else if constexpr (N==4)  asm volatile("s_waitcnt vmcnt(4)" ::: "memory");
  else if constexpr (N==6)  asm volatile("s_waitcnt vmcnt(6)" ::: "memory");
  else if constexpr (N==8)  asm volatile("s_waitcnt vmcnt(8)" ::: "memory");
  else if constexpr (N==12) asm volatile("s_waitcnt vmcnt(12)" ::: "memory");
}

// ---------------------------------------------------------------------------
// ONE prep launch (64x64 tiles, full-128B-line packed stores) + kv converts
// + fused embed+LN tail blocks. Transpose-range XCD swizzle (kept, ~neutral).
// Blocks [0,14336): transposes. [14336,22528): converts. [22528,24576): embed.
// prep is at its practical floor (~107us) after r9/r12/r19/r22 experiments.
// ---------------------------------------------------------------------------
__global__ __launch_bounds__(256) void prep_all(
    const float* __restrict__ Wq, const float* __restrict__ Wk,
    const float* __restrict__ Wv, const float* __restrict__ Wo,
    const float* __restrict__ W1, const float* __restrict__ W2,
    const float* __restrict__ g_db, const float* __restrict__ g_con,
    const float* __restrict__ g_usr, const float* __restrict__ g_enc,
    u16* __restrict__ dst0,
    u16* __restrict__ kvb0, u16* __restrict__ kvb1,
    u16* __restrict__ kvb2, u16* __restrict__ kvb3,
    const float* __restrict__ emb, const int* __restrict__ pvec,
    const float* __restrict__ pos, u16* __restrict__ xbout)
{
  const int fid = blockIdx.x;
  const int bid = (fid < 14336) ? ((fid & 7) * 1792 + (fid >> 3)) : fid;
  const int tid = threadIdx.x;
  if (bid >= 22528){                       // ---- fused embed + LN ----
    const int row = bid - 22528;
    const int lane = tid & 63, wid = tid >> 6;
    const int idx = pvec[row];
    const int t = row & (TT - 1);
    float4 e = ((const float4*)(emb + (long)idx * DD))[tid];
    float4 p = ((const float4*)(pos + (long)t * DD))[tid];
    float4 x;
    x.x = e.x * 32.0f + p.x; x.y = e.y * 32.0f + p.y;
    x.z = e.z * 32.0f + p.z; x.w = e.w * 32.0f + p.w;
    float s = x.x + x.y + x.z + x.w;
    #pragma unroll
    for (int o = 32; o; o >>= 1) s += __shfl_xor(s, o);
    __shared__ float red[4];
    if (lane == 0) red[wid] = s;
    __syncthreads();
    const float mean = (red[0] + red[1] + red[2] + red[3]) * (1.0f / DD);
    __syncthreads();
    const float dx = x.x - mean, dy = x.y - mean, dz = x.z - mean, dw = x.w - mean;
    float q = dx*dx + dy*dy + dz*dz + dw*dw;
    #pragma unroll
    for (int o = 32; o; o >>= 1) q += __shfl_xor(q, o);
    if (lane == 0) red[wid] = q;
    __syncthreads();
    const float var = (red[0] + red[1] + red[2] + red[3]) * (1.0f / DD);
    const float rstd = rsqrtf(var + 1e-5f);
    ushort4 o4;
    o4.x = f2bf(dx*rstd); o4.y = f2bf(dy*rstd);
    o4.z = f2bf(dz*rstd); o4.w = f2bf(dw*rstd);
    ((ushort4*)(xbout + (long)row * DD))[tid] = o4;
    return;
  }
  if (bid >= 14336){                       // ---- kv convert ----
    const int r = bid - 14336;
    const float* s; u16* d;
    switch (r >> 11){
      case 0: s = g_db;  d = kvb0; break;
      case 1: s = g_con; d = kvb1; break;
      case 2: s = g_usr; d = kvb2; break;
      default: s = g_enc; d = kvb3; break;
    }
    const int i = (r & 2047) * 256 + tid;
    float4 v = ((const float4*)s)[i];
    ushort4 o;
    o.x = f2bf(v.x); o.y = f2bf(v.y); o.z = f2bf(v.z); o.w = f2bf(v.w);
    ((ushort4*)d)[i] = o;
    return;
  }
  constexpr long D2 = (long)DD * DD, DF = (long)DD * FF;
  constexpr long O_Wproj = 0, O_WkvC = 14*D2, O_WoT = 30*D2,
                 O_W1T = 40*D2, O_W2T = 40*D2 + 2*DF;
  const float* src; long soff, doff; int R, C, rem;
  if (bid < 1536){                         // self Wq/Wk/Wv (j) x layer (l)
    const int j = bid / 512;
    src = (j==0) ? Wq : (j==1) ? Wk : Wv;
    const int l = (bid % 512) / 256; rem = bid & 255;
    soff = (long)l * 5 * D2;
    doff = O_Wproj + (long)l * 7 * D2 +
           ((j==0) ? 0L : (j==1) ? 5L*D2 : 6L*D2);
    R = DD; C = DD;
  } else if (bid < 5632){                  // cross K/V: (l, ci, kv)
    const int idx = (bid - 1536) >> 8; rem = bid & 255;
    const int l = idx >> 3, ci = (idx >> 1) & 3, kv = idx & 1;
    src = kv ? Wv : Wk;
    soff = (long)(l*5 + 1 + ci) * D2;
    doff = O_WkvC + (long)(l*8 + ci*2 + kv) * D2;
    R = DD; C = DD;
  } else if (bid < 7680){                  // cross Q: (l, ci) -> slot 1+ci
    const int idx = (bid - 5632) >> 8; rem = bid & 255;
    const int l = idx >> 2, ci = idx & 3;
    src = Wq;
    soff = (long)(l*5 + 1 + ci) * D2;
    doff = O_Wproj + (long)l * 7 * D2 + (long)(1 + ci) * D2;
    R = DD; C = DD;
  } else if (bid < 10240){                 // Wo (10 matrices)
    const int idx = (bid - 7680) >> 8; rem = bid & 255;
    src = Wo; soff = (long)idx * D2; doff = O_WoT + (long)idx * D2;
    R = DD; C = DD;
  } else if (bid < 12288){                 // W1 [DD][FF], z=2
    const int b5 = bid - 10240;
    const int z = b5 >> 10; rem = b5 & 1023;
    src = W1; soff = (long)z * DF; doff = O_W1T + (long)z * DF;
    R = DD; C = FF;
  } else {                                 // W2 [FF][DD], z=2
    const int b6 = bid - 12288;
    const int z = b6 >> 10; rem = b6 & 1023;
    src = W2; soff = (long)z * DF; doff = O_W2T + (long)z * DF;
    R = FF; C = DD;
  }
  const int ctiles = C >> 6;
  const int c0 = (rem % ctiles) << 6;
  const int r0 = (rem / ctiles) << 6;

  __shared__ u16 tile[64][66];
  const int tr = tid >> 4, tc = tid & 15;
  #pragma unroll
  for (int i = 0; i < 4; ++i){
    const int row = tr + i*16;
    float4 v = ((const float4*)(src + soff + (long)(r0 + row)*C + c0))[tc];
    unsigned* t32 = (unsigned*)&tile[row][tc*4];
    t32[0] = (unsigned)f2bf(v.x) | ((unsigned)f2bf(v.y) << 16);
    t32[1] = (unsigned)f2bf(v.z) | ((unsigned)f2bf(v.w) << 16);
  }
  __syncthreads();
  const int ch = tid & 7;
  const int cb = tid >> 3;                 // 0..31
  #pragma unroll
  for (int it = 0; it < 2; ++it){
    const int cc = cb + it*32;             // output row = source col
    union { int4 v; u16 u[8]; } P;
    #pragma unroll
    for (int j = 0; j < 8; ++j) P.u[j] = tile[ch*8 + j][cc];
    *(int4*)&dst0[doff + (long)(c0 + cc)*R + r0 + ch*8] = P.v;
  }
}

// ---------------------------------------------------------------------------
// Chained residual+LN: x = LN(...LN(LN(x + o0) + o1)... + o4), f32 registers.
// ---------------------------------------------------------------------------
__global__ __launch_bounds__(256) void ln_chain5(
    const float* __restrict__ o5, u16* __restrict__ xb)
{
  const int row = blockIdx.x;
  const int i = threadIdx.x;
  const int lane = i & 63, wid = i >> 6;
  __shared__ float red[4];
  constexpr long NB = (long)2048 * 1024;
  ushort4 x4 = ((const ushort4*)(xb + (long)row * DD))[i];
  float4 x;
  x.x = bf2f(x4.x); x.y = bf2f(x4.y); x.z = bf2f(x4.z); x.w = bf2f(x4.w);
  #pragma unroll
  for (int it = 0; it < 5; ++it){
    float4 o = ((const float4*)(o5 + (long)it * NB + (long)row * DD))[i];
    x.x += o.x; x.y += o.y; x.z += o.z; x.w += o.w;
    float s = x.x + x.y + x.z + x.w;
    #pragma unroll
    for (int off = 32; off; off >>= 1) s += __shfl_xor(s, off);
    if (lane == 0) red[wid] = s;
    __syncthreads();
    const float mean = (red[0] + red[1] + red[2] + red[3]) * (1.0f / DD);
    __syncthreads();
    x.x -= mean; x.y -= mean; x.z -= mean; x.w -= mean;
    float q = x.x*x.x + x.y*x.y + x.z*x.z + x.w*x.w;
    #pragma unroll
    for (int off = 32; off; off >>= 1) q += __shfl_xor(q, off);
    if (lane == 0) red[wid] = q;
    __syncthreads();
    const float var = (red[0] + red[1] + red[2] + red[3]) * (1.0f / DD);
    const float rstd = rsqrtf(var + 1e-5f);
    x.x *= rstd; x.y *= rstd; x.z *= rstd; x.w *= rstd;
    __syncthreads();
  }
  ushort4 o4;
  o4.x = f2bf(x.x); o4.y = f2bf(x.y); o4.z = f2bf(x.z); o4.w = f2bf(x.w);
  ((ushort4*)(xb + (long)row * DD))[i] = o4;
}

// ---------------------------------------------------------------------------
// LayerNorm(a) -> yf (f32, optional) and yb (bf16, optional)
// ---------------------------------------------------------------------------
__global__ __launch_bounds__(256) void ln_kernel(
    const float* __restrict__ a,
    float* __restrict__ yf, u16* __restrict__ yb)
{
  const int row = blockIdx.x;
  const int i = threadIdx.x;
  const int lane = i & 63, wid = i >> 6;
  float4 x = ((const float4*)(a + (long)row * DD))[i];
  float s = x.x + x.y + x.z + x.w;
  #pragma unroll
  for (int o = 32; o; o >>= 1) s += __shfl_xor(s, o);
  __shared__ float red[4];
  if (lane == 0) red[wid] = s;
  __syncthreads();
  const float mean = (red[0] + red[1] + red[2] + red[3]) * (1.0f / DD);
  __syncthreads();
  const float dx = x.x - mean, dy = x.y - mean, dz = x.z - mean, dw = x.w - mean;
  float q = dx*dx + dy*dy + dz*dz + dw*dw;
  #pragma unroll
  for (int o = 32; o; o >>= 1) q += __shfl_xor(q, o);
  if (lane == 0) red[wid] = q;
  __syncthreads();
  const float var = (red[0] + red[1] + red[2] + red[3]) * (1.0f / DD);
  const float rstd = rsqrtf(var + 1e-5f);
  float4 y; y.x = dx*rstd; y.y = dy*rstd; y.z = dz*rstd; y.w = dw*rstd;
  if (yf) ((float4*)(yf + (long)row * DD))[i] = y;
  if (yb){
    ushort4 o4; o4.x = f2bf(y.x); o4.y = f2bf(y.y); o4.z = f2bf(y.z); o4.w = f2bf(y.w);
    ((ushort4*)(yb + (long)row * DD))[i] = o4;
  }
}

// ---------------------------------------------------------------------------
// Flash attention core (shared). T13 defer-max (THR=8): skip accO/lrow
// rescale when no row's max grew by >8 — P bounded by e^8; bf16/f32 errors
// are relative, final /lrow normalizes exactly.
// ---------------------------------------------------------------------------
template<bool CAUSAL>
__device__ __forceinline__ void flash_body(
    const u16* Q, const u16* Kt, const u16* Vt,
    const float* biasS, u16* O,
    int qt, int bh, u16 (*Ks)[64*64], u16 (*Vs)[64*64], u16* Ps)
{
  const int b = bh >> 4, h = bh & 15;
  const int tid = threadIdx.x, lane = tid & 63, wid = tid >> 6;
  const int fr = lane & 15, kg = lane >> 4;
  const int srow = tid >> 3;
  const int gcol = ((tid & 7) ^ (srow & 7)) * 8;
  u16* Pw = Ps + wid * 1024;
  const facc4 z4 = {0.0f, 0.0f, 0.0f, 0.0f};

  const long base = (long)bh * (512 * 64);
  const u16* qrow = Q + base + (long)(qt*64 + wid*16 + fr) * 64;
  const bfrag8 aq0 = *(const bfrag8*)(qrow + kg*8);
  const bfrag8 aq1 = *(const bfrag8*)(qrow + 32 + kg*8);

  auto stageKV = [&](int buf, int kt){
    u16* Kd = Ks[buf] + wid * 512;
    u16* Vd = Vs[buf] + wid * 512;
    #pragma unroll
    for (int p = 0; p < 2; ++p)
      gload16(Kt + base + (long)(kt*64 + p*32 + srow) * 64 + gcol, Kd + p*2048);
    #pragma unroll
    for (int p = 0; p < 2; ++p)
      gload16(Vt + base + (long)(p*32 + srow) * 512 + kt*64 + gcol, Vd + p*2048);
  };

  float mrow[4], lrow[4];
  #pragma unroll
  for (int r = 0; r < 4; ++r){ mrow[r] = -3e38f; lrow[r] = 0.0f; }
  facc4 accO[4] = {};

  const int NT = CAUSAL ? (qt + 1) : 8;
  stageKV(0, 0);
  if (NT > 1){ stageKV(1, 1); vwait<4>(); }
  else vwait<0>();
  __builtin_amdgcn_s_barrier();

  for (int kt = 0; kt < NT; ++kt){
    const int cur = kt & 1;
    bfrag8 bk[4][2], bv[4][2];
    #pragma unroll
    for (int j = 0; j < 4; ++j)
      #pragma unroll
      for (int c2 = 0; c2 < 2; ++c2){
        const int po = (((c2*4 + kg) ^ (fr & 7)) * 8);
        bk[j][c2] = *(const bfrag8*)&Ks[cur][(j*16 + fr)*64 + po];
        bv[j][c2] = *(const bfrag8*)&Vs[cur][(j*16 + fr)*64 + po];
      }
    __builtin_amdgcn_sched_barrier(0);
    __builtin_amdgcn_s_barrier();
    if (kt + 2 < NT){ stageKV(cur, kt + 2); vwait<4>(); }
    else vwait<0>();
    __builtin_amdgcn_s_barrier();

    // QK^T
    facc4 sc[4];
    __builtin_amdgcn_s_setprio(1);
    #pragma unroll
    for (int j = 0; j < 4; ++j){
      sc[j] = __builtin_amdgcn_mfma_f32_16x16x32_bf16(aq0, bk[j][0], z4, 0, 0, 0);
      sc[j] = __builtin_amdgcn_mfma_f32_16x16x32_bf16(aq1, bk[j][1], sc[j], 0, 0, 0);
    }
    __builtin_amdgcn_s_setprio(0);
    if (CAUSAL){
      const int rowb = qt*64 + wid*16 + kg*4;
      #pragma unroll
      for (int j = 0; j < 4; ++j){
        const int col = kt*64 + j*16 + fr;
        #pragma unroll
        for (int r = 0; r < 4; ++r)
          if (col > rowb + r) sc[j][r] = -1e20f;
      }
    } else {
      #pragma unroll
      for (int j = 0; j < 4; ++j){
        const float bval = biasS[kt*64 + j*16 + fr];
        #pragma unroll
        for (int r = 0; r < 4; ++r) sc[j][r] += bval;
      }
    }
    // online softmax with defer-max (T13, THR=8)
    float tmax[4];
    #pragma unroll
    for (int r = 0; r < 4; ++r)
      tmax[r] = fmaxf(fmaxf(sc[0][r], sc[1][r]), fmaxf(sc[2][r], sc[3][r]));
    #pragma unroll
    for (int o = 1; o < 16; o <<= 1)
      #pragma unroll
      for (int r = 0; r < 4; ++r)
        tmax[r] = fmaxf(tmax[r], __shfl_xor(tmax[r], o));
    bool grow = false;
    #pragma unroll
    for (int r = 0; r < 4; ++r) grow = grow || (tmax[r] > mrow[r] + 8.0f);
    if (__any(grow)){
      float fac[4];
      #pragma unroll
      for (int r = 0; r < 4; ++r){
        const float mn = fmaxf(mrow[r], tmax[r]);
        fac[r] = __expf(mrow[r] - mn);
        mrow[r] = mn;
        lrow[r] *= fac[r];
      }
      #pragma unroll
      for (int f = 0; f < 4; ++f)
        #pragma unroll
        for (int r = 0; r < 4; ++r) accO[f][r] *= fac[r];
    }
    float tsum[4] = {0.0f, 0.0f, 0.0f, 0.0f};
    #pragma unroll
    for (int j = 0; j < 4; ++j)
      #pragma unroll
      for (int r = 0; r < 4; ++r){
        const float p = __expf(sc[j][r] - mrow[r]);
        sc[j][r] = p; tsum[r] += p;
      }
    #pragma unroll
    for (int o = 1; o < 16; o <<= 1)
      #pragma unroll
      for (int r = 0; r < 4; ++r) tsum[r] += __shfl_xor(tsum[r], o);
    #pragma unroll
    for (int r = 0; r < 4; ++r) lrow[r] += tsum[r];

    // P -> wave-private LDS (chunk-swizzled), read back as A-frags
    #pragma unroll
    for (int j = 0; j < 4; ++j)
      #pragma unroll
      for (int r = 0; r < 4; ++r){
        const int row = kg*4 + r;
        const int col = j*16 + fr;
        Pw[row*64 + (((col >> 3) ^ (row & 7)) * 8) + (col & 7)] = f2bf(sc[j][r]);
      }
    bfrag8 ap[2];
    #pragma unroll
    for (int c2 = 0; c2 < 2; ++c2)
      ap[c2] = *(const bfrag8*)&Pw[fr*64 + (((c2*4 + kg) ^ (fr & 7)) * 8)];
    __builtin_amdgcn_s_setprio(1);
    #pragma unroll
    for (int f = 0; f < 4; ++f){
      accO[f] = __builtin_amdgcn_mfma_f32_16x16x32_bf16(ap[0], bv[f][0], accO[f], 0, 0, 0);
      accO[f] = __builtin_amdgcn_mfma_f32_16x16x32_bf16(ap[1], bv[f][1], accO[f], 0, 0, 0);
    }
    __builtin_amdgcn_s_setprio(0);
  }

  // epilogue: O/lrow via Pw bounce -> coalesced 16B stores
  #pragma unroll
  for (int f = 0; f < 4; ++f)
    #pragma unroll
    for (int r = 0; r < 4; ++r){
      const int row = kg*4 + r;
      const int col = f*16 + fr;
      Pw[(row*64 + col) ^ ((row & 7) << 3)] = f2bf(accO[f][r] / lrow[r]);
    }
  const int prow = lane >> 2, pch = lane & 3;
  const long orow = (long)(b*512 + qt*64 + wid*16 + prow) * 1024 + h*64;
  #pragma unroll
  for (int it2 = 0; it2 < 2; ++it2){
    const int ch2 = pch + it2*4;
    int4 w4 = *(const int4*)&Pw[(prow*64 + ch2*8) ^ ((prow & 7) << 3)];
    *(int4*)&O[orow + ch2*8] = w4;
  }
}

// ---- ALL 5 attentions in one launch, grid (8,64,5); z=0 self, z>=1 cross ----
__global__ __launch_bounds__(256, 3) void flash_all5(
    const u16* __restrict__ Qb5, const u16* __restrict__ Kb,
    const u16* __restrict__ Vtb, const u16* __restrict__ KVcl,
    const int* __restrict__ cmask, u16* __restrict__ O5)
{
  __shared__ __align__(16) u16 Ks[2][64*64];
  __shared__ __align__(16) u16 Vs[2][64*64];
  __shared__ __align__(16) u16 Ps[4*16*64];
  __shared__ float biasS[512];
  const int z = blockIdx.z;
  const int fid = blockIdx.y * 8 + blockIdx.x;
  const int lid = (fid & 7) * 64 + (fid >> 3);
  const int qt = lid & 7, bh = lid >> 3;
  constexpr long NB = (long)2048 * 1024;
  if (z == 0){
    flash_body<true>(Qb5, Kb, Vtb, nullptr, O5, qt, bh, Ks, Vs, Ps);
  } else {
    const int ci = z - 1;
    const int mode = (0x0312 >> (ci*4)) & 0xF;   // ci: 0->2, 1->1, 2->3, 3->0
    const int b = bh >> 4;
    const int tid = threadIdx.x;
    #pragma unroll
    for (int r = 0; r < 2; ++r){
      const int c = r * 256 + tid;
      biasS[c] = (cmask[b * 512 + c] != mode) ? 0.0f : -1e20f;
    }
    __syncthreads();
    flash_body<false>(Qb5 + (long)z * NB,
                      KVcl + (long)(ci*2) * NB, KVcl + (long)(ci*2 + 1) * NB,
                      biasS, O5 + (long)z * NB, qt, bh, Ks, Vs, Ps);
  }
}

// ---------------------------------------------------------------------------
#define MODE_F32   0
#define MODE_BF16  1
#define MODE_KV    4
#define MODE_PROJ  6
#define MODE_F32B  7

__device__ __forceinline__ long qk_off(int gm, int gn){   // [b,h,t,d]
  return (((long)(gm >> 9) * HH + (gn >> 6)) * TT + (gm & (TT-1))) * DHH + (gn & (DHH-1));
}

// ---------------------------------------------------------------------------
// 256-thread bf16 MFMA GEMM, BK=64, counted-vmcnt pipeline, XCD swizzle.
// NBUF=3 for 64x64 tiles; 2 otherwise. 128x128: 32 MFMA : 16 ds_read/step.
// (r23's m97-structure BK=32 single-buffer regressed −16us: full drain per
//  32-K step costs more than the extra occupancy buys at K=1024. REVERTED.)
// ---------------------------------------------------------------------------
template<int BM, int BN, int MODE>
__global__ __launch_bounds__(256, 2) void gemm_k(
    const u16* __restrict__ A, const u16* __restrict__ B,
    const float* __restrict__ bias0, const float* __restrict__ bias1,
    const float* __restrict__ bias2,
    float* __restrict__ Cf, u16* __restrict__ Cb0, u16* __restrict__ Cb1,
    u16* __restrict__ Cb2, const u16* __restrict__ resb,
    int K, int lda, int ldb, int ldc,
    int relu, float alpha)
{
  constexpr int BK = 64;
  constexpr int NBUF = (BM == 64 && BN == 64) ? 3 : 2;
  constexpr int ASZ = BM * BK, BSZ = BN * BK;
  __shared__ __align__(16) u16 As[NBUF * ASZ];
  __shared__ __align__(16) u16 Bs[NBUF * BSZ];

  const int gx = gridDim.x, gy = gridDim.y;
  const int nwg = gx * gy * gridDim.z;
  const int fid = (blockIdx.z * gy + blockIdx.y) * gx + blockIdx.x;
  const int cpx = nwg >> 3;
  const int lid = (fid & 7) * cpx + (fid >> 3);
  const int bx = lid % gx;
  const int rem = lid / gx;
  const int by = rem % gy;
  const int z  = rem / gy;

  const u16* Ab;
  const u16* Bb;
  long cbase;
  constexpr long NBA = (long)2048 * 1024;
  constexpr long D2C = (long)DD * DD;
  if constexpr (MODE == MODE_KV){
    const int ci = z >> 2, ll = (z >> 1) & 1, isv = z & 1;
    Ab = A + (long)ci * NBA;
    Bb = B + (long)(ll*8 + ci*2 + isv) * D2C;
    cbase = (long)(ll*8 + ci*2 + isv) * NBA;
  } else if constexpr (MODE == MODE_F32B){
    Ab = A + (long)z * NBA;
    Bb = B + (long)z * D2C;
    cbase = (long)z * NBA;
  } else {
    Ab = A; Bb = B; cbase = 0;
  }
  const int tid = threadIdx.x, lane = tid & 63, wid = tid >> 6;
  const int m0 = by * BM, n0 = bx * BN;
  constexpr int TMW = BM / 2, TNW = BN / 2;           // 2x2 wave grid
  constexpr int FM = TMW / 16, FN = TNW / 16;
  const int wm = (wid >> 1) * TMW, wn = (wid & 1) * TNW;
  const int fr = lane & 15, kg = lane >> 4;
  facc4 acc[FM][FN] = {};

  const int srow = tid >> 3;
  const int gcol = (((tid & 7) ^ (srow & 7)) * 8);
  constexpr int AP = BM / 32, BP = BN / 32;
  constexpr int LPS = AP + BP;

  auto stage = [&](int buf, int k0){
    u16* Ad = As + buf * ASZ + wid * 512;
    u16* Bd = Bs + buf * BSZ + wid * 512;
    #pragma unroll
    for (int p = 0; p < AP; ++p)
      gload16(Ab + (long)(m0 + p*32 + srow) * lda + (k0 + gcol), Ad + p*2048);
    #pragma unroll
    for (int p = 0; p < BP; ++p)
      gload16(Bb + (long)(n0 + p*32 + srow) * ldb + (k0 + gcol), Bd + p*2048);
  };

  const int nsteps = K / BK;
  stage(0, 0);
  if constexpr (NBUF == 3){
    if (nsteps > 1) stage(1, BK);
    if (nsteps > 2) stage(2, 2*BK);
    if (nsteps > 2) vwait<2*LPS>();
    else if (nsteps > 1) vwait<LPS>();
    else vwait<0>();
  } else {
    if (nsteps > 1){ stage(1, BK); vwait<LPS>(); }
    else vwait<0>();
  }
  __builtin_amdgcn_s_barrier();

  int cur = 0;
  for (int s = 0; s < nsteps; ++s){
    const u16* Ar = As + cur * ASZ;
    const u16* Br = Bs + cur * BSZ;
    bfrag8 af[FM][2], bfv[FN][2];
    #pragma unroll
    for (int i = 0; i < FM; ++i)
      #pragma unroll
      for (int c2 = 0; c2 < 2; ++c2)
        af[i][c2] = *(const bfrag8*)&Ar[(wm + i*16 + fr) * 64 + (((c2*4 + kg) ^ (fr & 7)) * 8)];
    #pragma unroll
    for (int j = 0; j < FN; ++j)
      #pragma unroll
      for (int c2 = 0; c2 < 2; ++c2)
        bfv[j][c2] = *(const bfrag8*)&Br[(wn + j*16 + fr) * 64 + (((c2*4 + kg) ^ (fr & 7)) * 8)];
    __builtin_amdgcn_sched_barrier(0);
    __builtin_amdgcn_s_barrier();
    if constexpr (NBUF == 3){
      if (s + 3 < nsteps){ stage(cur, (s + 3) * BK); vwait<2*LPS>(); }
      else if (s + 2 < nsteps) vwait<LPS>();
      else if (s + 1 < nsteps) vwait<0>();
    } else {
      if (s + 2 < nsteps){ stage(cur, (s + 2) * BK); vwait<LPS>(); }
      else if (s + 1 < nsteps) vwait<0>();
    }
    __builtin_amdgcn_s_barrier();
    #pragma unroll
    for (int i = 0; i < FM; ++i)
      #pragma unroll
      for (int j = 0; j < FN; ++j){
        acc[i][j] = __builtin_amdgcn_mfma_f32_16x16x32_bf16(af[i][0], bfv[j][0], acc[i][j], 0, 0, 0);
        acc[i][j] = __builtin_amdgcn_mfma_f32_16x16x32_bf16(af[i][1], bfv[j][1], acc[i][j], 0, 0, 0);
      }
    cur = (cur == NBUF - 1) ? 0 : cur + 1;
  }

  // ---- V^T output path: LDS transpose bounce -> coalesced stores ----
  if constexpr (MODE == MODE_KV || MODE == MODE_PROJ){
    const float* vb = nullptr; u16* vdst = nullptr; int n0e = 0; bool vpath = false;
    if constexpr (MODE == MODE_KV){
      const int ci = z >> 2, ll = (z >> 1) & 1, isv = z & 1;
      if (isv){ vpath = true; vb = bias1 + (long)(ll*5 + ci + 1) * DD; vdst = Cb0 + cbase; n0e = n0; }
    } else {
      if ((n0 >> 10) == 6){ vpath = true; vb = bias2; vdst = Cb2; n0e = n0 - 6144; }
    }
    if (vpath){
      u16* S = Bs;
      #pragma unroll
      for (int j = 0; j < FN; ++j){
        const int nl = wn + j*16 + fr;
        const float bvv = vb[n0e + nl];
        #pragma unroll
        for (int i = 0; i < FM; ++i)
          #pragma unroll
          for (int rr = 0; rr < 4; ++rr){
            const int ml = wm + i*16 + kg*4 + rr;
            S[(nl*BM + ml) ^ ((nl & 7) << 3)] = f2bf(acc[i][j][rr] + bvv);
          }
      }
      __syncthreads();
      constexpr int TPR = 256 / BN;
      constexpr int CPT = BM / (8 * TPR);
      const int n = tid / TPR;
      const int mh = (tid % TPR) * (BM / TPR);
      const long rowoff = (((long)(m0 >> 9) * HH + ((n0e + n) >> 6)) * DHH
                           + ((n0e + n) & 63)) * TT + (m0 & 511) + mh;
      #pragma unroll
      for (int c = 0; c < CPT; ++c){
        int4 w4 = *(const int4*)&S[(n*BM + mh + c*8) ^ ((n & 7) << 3)];
        *(int4*)&vdst[rowoff + c*8] = w4;
      }
      return;
    }
  }

  // ---- bf16 row-major bounce (MODE_BF16 / PROJ Q,K / KV K-side) ----
  if constexpr (MODE == MODE_BF16 || MODE == MODE_PROJ || MODE == MODE_KV){
    u16* S = As;                 // NBUF*ASZ u16 >= BM*BN u16 for all configs
    const float* bp = bias0;
    float sc2 = alpha;
    u16* dst = Cb0;
    int nb = 0;
    constexpr long NBA2 = (long)2048 * 1024;
    if constexpr (MODE == MODE_KV){
      const int ci = z >> 2, ll = (z >> 1) & 1;
      bp = bias0 + (long)(ll*5 + ci + 1) * DD;
    } else if constexpr (MODE == MODE_PROJ){
      const int sect = n0 >> 10;           // 0..5 here (128 | 1024 -> no straddle)
      nb = n0 & 1023;
      if (sect <= 4){ bp = bias0 + (long)sect * DD; sc2 = 0.125f; dst = Cb0 + (long)sect * NBA2; }
      else          { bp = bias1; sc2 = 1.0f; dst = Cb1; }
    }
    #pragma unroll
    for (int i = 0; i < FM; ++i)
      #pragma unroll
      for (int j = 0; j < FN; ++j){
        const int nl = wn + j*16 + fr;
        float bvv;
        if constexpr (MODE == MODE_PROJ) bvv = bp[nb + nl];
        else bvv = bp ? bp[n0 + nl] : 0.0f;
        #pragma unroll
        for (int rr = 0; rr < 4; ++rr){
          const int ml = wm + i*16 + kg*4 + rr;
          float v = (acc[i][j][rr] + bvv) * sc2;
          if (relu) v = fmaxf(v, 0.0f);
          S[(ml*BN + nl) ^ ((ml & 7) << 3)] = f2bf(v);
        }
      }
    __syncthreads();
    constexpr int CPR = BN / 8;                 // 16B chunks per row
    constexpr int NIT = (BM * CPR) / 256;
    #pragma unroll
    for (int it = 0; it < NIT; ++it){
      const int idx = it * 256 + tid;
      const int row = idx / CPR, ch = idx % CPR;
      int4 w4 = *(const int4*)&S[(row*BN + ch*8) ^ ((row & 7) << 3)];
      const int gm = m0 + row;
      long off;
      if constexpr (MODE == MODE_BF16) off = cbase + (long)gm * ldc + (n0 + ch*8);
      else if constexpr (MODE == MODE_PROJ) off = qk_off(gm, nb + ch*8);
      else off = cbase + qk_off(gm, n0 + ch*8);
      *(int4*)&dst[off] = w4;
    }
    return;
  }

  // Epilogue (MODE_F32 / MODE_F32B). C/D layout: col = fr, row = kg*4 + rr.
  {
    const float* bp0 = bias0;
    if constexpr (MODE == MODE_F32B) bp0 = bias0 + (long)z * DD;
    #pragma unroll
    for (int i = 0; i < FM; ++i){
      #pragma unroll
      for (int j = 0; j < FN; ++j){
        const int gn = n0 + wn + j*16 + fr;
        #pragma unroll
        for (int rr = 0; rr < 4; ++rr){
          const int gm = m0 + wm + i*16 + kg*4 + rr;
          float v = acc[i][j][rr];
          v = (v + (bp0 ? bp0[gn] : 0.0f)) * alpha;
          if (relu) v = fmaxf(v, 0.0f);
          const long off = cbase + (long)gm * ldc + gn;
          if constexpr (MODE == MODE_F32){
            if (resb) v += bf2f(resb[off]);        // fused bf16 residual
          }
          Cf[off] = v;
        }
      }
    }
  }
}

// ---------------------------------------------------------------------------
extern "C" void kernel_launch(void* const* d_in, const int* in_sizes, int n_in,
                              void* d_out, int out_size, void* d_ws, size_t ws_size,
                              hipStream_t stream)
{
  (void)in_sizes; (void)n_in; (void)out_size; (void)ws_size;
  const float* emb   = (const float*)d_in[0];
  const int*   pvec  = (const int*)d_in[1];
  const float* g_enc = (const float*)d_in[2];
  const float* g_con = (const float*)d_in[3];
  const float* g_db  = (const float*)d_in[4];
  const float* g_usr = (const float*)d_in[5];
  const int*   cmask = (const int*)d_in[6];
  const float* pose  = (const float*)d_in[7];
  const float* Wq = (const float*)d_in[8];
  const float* bq = (const float*)d_in[9];
  const float* Wk = (const float*)d_in[10];
  const float* bk = (const float*)d_in[11];
  const float* Wv = (const float*)d_in[12];
  const float* bv = (const float*)d_in[13];
  const float* Wo = (const float*)d_in[14];
  const float* bo = (const float*)d_in[15];
  const float* W1 = (const float*)d_in[16];
  const float* b1 = (const float*)d_in[17];
  const float* W2 = (const float*)d_in[18];
  const float* b2 = (const float*)d_in[19];
  float* out = (float*)d_out;

  const size_t NTOK = (size_t)BB * TT;   // 2048
  const long D2 = (long)DD * DD;

  char* wp = (char*)d_ws;
  auto alloc = [&](size_t bytes) -> char* {
    char* p = wp;
    wp += (bytes + 255) & ~(size_t)255;
    return p;
  };
  // NOTE: the first 5 arrays' order/offsets are hard-coded in prep_all.
  u16*   WprojT = (u16*) alloc(sizeof(u16) * 2 * 7 * D2);   // [l][7 slots]
  u16*   WkvC   = (u16*) alloc(sizeof(u16) * 2 * 4 * 2 * D2);
  u16*   WoT    = (u16*) alloc(sizeof(u16) * 10 * D2);
  u16*   W1T    = (u16*) alloc(sizeof(u16) * 2 * DD * FF);
  u16*   W2T    = (u16*) alloc(sizeof(u16) * 2 * DD * FF);
  // kvb0..3 MUST stay contiguous: MODE_KV indexes them as [4][NTOK][DD]
  u16*   kvb0  = (u16*)  alloc(sizeof(u16) * NTOK * DD);
  u16*   kvb1  = (u16*)  alloc(sizeof(u16) * NTOK * DD);
  u16*   kvb2  = (u16*)  alloc(sizeof(u16) * NTOK * DD);
  u16*   kvb3  = (u16*)  alloc(sizeof(u16) * NTOK * DD);
  u16*   KVc   = (u16*)  alloc(sizeof(u16) * 16 * NTOK * DD);
  u16*   xb    = (u16*)  alloc(sizeof(u16) * NTOK * DD);
  u16*   Qb5   = (u16*)  alloc(sizeof(u16) * 5 * NTOK * DD);
  u16*   Kb    = (u16*)  alloc(sizeof(u16) * NTOK * DD);
  u16*   Vtb   = (u16*)  alloc(sizeof(u16) * NTOK * DD);
  u16*   attnb5= (u16*)  alloc(sizeof(u16) * 5 * NTOK * DD);
  float* oproj5= (float*)alloc(sizeof(float) * 5 * NTOK * DD);
  float* obuf  = (float*)alloc(sizeof(float) * NTOK * DD);
  u16*   hb    = (u16*)  alloc(sizeof(u16) * NTOK * FF);

  // ---- ONE prep launch: transposes + kv converts + embed/LN ----
  prep_all<<<24576, 256, 0, stream>>>(
      Wq, Wk, Wv, Wo, W1, W2, g_db, g_con, g_usr, g_enc,
      (u16*)d_ws, kvb0, kvb1, kvb2, kvb3,
      emb, pvec, pose, xb);

  // ---- all cross-attention K/V in ONE 2048-block launch (16 z-batches) ----
  const long NB = (long)NTOK * DD;
  gemm_k<128,128,MODE_KV><<<dim3(8,16,16), 256, 0, stream>>>(
    kvb0, WkvC, bk, bv, nullptr,
    nullptr, KVc, nullptr, nullptr, nullptr,
    DD, DD, DD, 0, 0, 1.0f);

  for (int l = 0; l < 2; ++l){
    // ---- batched projections: [Q x5 | K_self | V_self], N = 7168 ----
    gemm_k<128,128,MODE_PROJ><<<dim3(56,16,1), 256, 0, stream>>>(
      xb, WprojT + (long)l*7*D2,
      bq + (size_t)l*5*DD, bk + (size_t)l*5*DD, bv + (size_t)l*5*DD,
      nullptr, Qb5, Kb, Vtb, nullptr,
      DD, DD, DD, 0, 0, 1.0f);

    // ALL 5 attentions (self causal + 4 cross) in one launch
    flash_all5<<<dim3(8,64,5), 256, 0, stream>>>(
        Qb5, Kb, Vtb, KVc + (long)l*8*NB, cmask, attnb5);

    // ALL 5 O-projections batched (z = i), f32 out, 128x128 tiles
    gemm_k<128,128,MODE_F32B><<<dim3(8,16,5), 256, 0, stream>>>(
      attnb5, WoT + (long)l*5*D2,
      bo + (size_t)l*5*DD, nullptr, nullptr,
      oproj5, nullptr, nullptr, nullptr, nullptr,
      DD, DD, DD, DD, 0, 1.0f);

    // chained residual+LN (one launch, f32 registers across 5 steps)
    ln_chain5<<<(int)NTOK, 256, 0, stream>>>(oproj5, xb);

    // FFN
    gemm_k<128,128,MODE_BF16><<<dim3(32,16,1), 256, 0, stream>>>(
      xb, W1T + (size_t)l*DD*FF,
      b1 + (size_t)l*FF, nullptr, nullptr,
      nullptr, hb, nullptr, nullptr, nullptr,
      DD, DD, DD, FF, 1, 1.0f);
    gemm_k<64,64,MODE_F32><<<dim3(16,32,1), 256, 0, stream>>>(
      hb, W2T + (size_t)l*DD*FF,
      b2 + (size_t)l*DD, nullptr, nullptr,
      obuf, nullptr, nullptr, nullptr, xb,
      FF, FF, FF, DD, 0, 1.0f);
    float* yf = (l == 1) ? out : nullptr;
    ln_kernel<<<(int)NTOK, 256, 0, stream>>>(obuf, yf, (l == 1) ? nullptr : xb);
  }
}

// Round 25
// 672.519 us; speedup vs baseline: 1.0265x; 1.0043x over previous
//
#include <hip/hip_runtime.h>

// Problem constants (Bert4KGModel): B=4, T=S=512, D=1024, H=16, dh=64, F=4096, L=2
#define BB  4
#define TT  512
#define DD  1024
#define HH  16
#define DHH 64
#define FF  4096

typedef unsigned short u16;
typedef __attribute__((ext_vector_type(8))) short bfrag8;   // 8 bf16 (4 VGPRs)
typedef __attribute__((ext_vector_type(4))) float facc4;    // 4 f32 acc

__device__ __forceinline__ u16 f2bf(float f){
  unsigned u = __float_as_uint(f);
  unsigned r = u + 0x7fffu + ((u >> 16) & 1u);   // RNE
  return (u16)(r >> 16);
}
__device__ __forceinline__ float bf2f(u16 h){
  return __uint_as_float(((unsigned)h) << 16);
}

// async global->LDS, 16B per lane; LDS dest is wave-uniform base + lane*16
__device__ __forceinline__ void gload16(const u16* g, u16* l){
  __builtin_amdgcn_global_load_lds(
      (const __attribute__((address_space(1))) void*)g,
      (__attribute__((address_space(3))) void*)l, 16, 0, 0);
}

// counted vmcnt wait (literal immediates only)
template<int N> __device__ __forceinline__ void vwait(){
  static_assert(N==0 || N==4 || N==6 || N==8 || N==12, "bad vmcnt literal");
  if constexpr (N==0)  asm volatile("s_waitcnt vmcnt(0)" ::: "memory");
  else if constexpr (N==4)  asm volatile("s_waitcnt vmcnt(4)" ::: "memory");
  else if constexpr (N==6)  asm volatile("s_waitcnt vmcnt(6)" ::: "memory");
  else if constexpr (N==8)  asm volatile("s_waitcnt vmcnt(8)" ::: "memory");
  else if constexpr (N==12) asm volatile("s_waitcnt vmcnt(12)" ::: "memory");
}

// ---------------------------------------------------------------------------
// ONE prep launch (64x64 tiles, full-128B-line packed stores) + kv converts
// + fused embed+LN tail blocks. Transpose-range XCD swizzle (kept, ~neutral).
// Blocks [0,14336): transposes. [14336,22528): converts. [22528,24576): embed.
// prep is at its practical floor (~107us) after r9/r12/r19/r22 experiments.
// ---------------------------------------------------------------------------
__global__ __launch_bounds__(256) void prep_all(
    const float* __restrict__ Wq, const float* __restrict__ Wk,
    const float* __restrict__ Wv, const float* __restrict__ Wo,
    const float* __restrict__ W1, const float* __restrict__ W2,
    const float* __restrict__ g_db, const float* __restrict__ g_con,
    const float* __restrict__ g_usr, const float* __restrict__ g_enc,
    u16* __restrict__ dst0,
    u16* __restrict__ kvb0, u16* __restrict__ kvb1,
    u16* __restrict__ kvb2, u16* __restrict__ kvb3,
    const float* __restrict__ emb, const int* __restrict__ pvec,
    const float* __restrict__ pos, u16* __restrict__ xbout)
{
  const int fid = blockIdx.x;
  const int bid = (fid < 14336) ? ((fid & 7) * 1792 + (fid >> 3)) : fid;
  const int tid = threadIdx.x;
  if (bid >= 22528){                       // ---- fused embed + LN ----
    const int row = bid - 22528;
    const int lane = tid & 63, wid = tid >> 6;
    const int idx = pvec[row];
    const int t = row & (TT - 1);
    float4 e = ((const float4*)(emb + (long)idx * DD))[tid];
    float4 p = ((const float4*)(pos + (long)t * DD))[tid];
    float4 x;
    x.x = e.x * 32.0f + p.x; x.y = e.y * 32.0f + p.y;
    x.z = e.z * 32.0f + p.z; x.w = e.w * 32.0f + p.w;
    float s = x.x + x.y + x.z + x.w;
    #pragma unroll
    for (int o = 32; o; o >>= 1) s += __shfl_xor(s, o);
    __shared__ float red[4];
    if (lane == 0) red[wid] = s;
    __syncthreads();
    const float mean = (red[0] + red[1] + red[2] + red[3]) * (1.0f / DD);
    __syncthreads();
    const float dx = x.x - mean, dy = x.y - mean, dz = x.z - mean, dw = x.w - mean;
    float q = dx*dx + dy*dy + dz*dz + dw*dw;
    #pragma unroll
    for (int o = 32; o; o >>= 1) q += __shfl_xor(q, o);
    if (lane == 0) red[wid] = q;
    __syncthreads();
    const float var = (red[0] + red[1] + red[2] + red[3]) * (1.0f / DD);
    const float rstd = rsqrtf(var + 1e-5f);
    ushort4 o4;
    o4.x = f2bf(dx*rstd); o4.y = f2bf(dy*rstd);
    o4.z = f2bf(dz*rstd); o4.w = f2bf(dw*rstd);
    ((ushort4*)(xbout + (long)row * DD))[tid] = o4;
    return;
  }
  if (bid >= 14336){                       // ---- kv convert ----
    const int r = bid - 14336;
    const float* s; u16* d;
    switch (r >> 11){
      case 0: s = g_db;  d = kvb0; break;
      case 1: s = g_con; d = kvb1; break;
      case 2: s = g_usr; d = kvb2; break;
      default: s = g_enc; d = kvb3; break;
    }
    const int i = (r & 2047) * 256 + tid;
    float4 v = ((const float4*)s)[i];
    ushort4 o;
    o.x = f2bf(v.x); o.y = f2bf(v.y); o.z = f2bf(v.z); o.w = f2bf(v.w);
    ((ushort4*)d)[i] = o;
    return;
  }
  constexpr long D2 = (long)DD * DD, DF = (long)DD * FF;
  constexpr long O_Wproj = 0, O_WkvC = 14*D2, O_WoT = 30*D2,
                 O_W1T = 40*D2, O_W2T = 40*D2 + 2*DF;
  const float* src; long soff, doff; int R, C, rem;
  if (bid < 1536){                         // self Wq/Wk/Wv (j) x layer (l)
    const int j = bid / 512;
    src = (j==0) ? Wq : (j==1) ? Wk : Wv;
    const int l = (bid % 512) / 256; rem = bid & 255;
    soff = (long)l * 5 * D2;
    doff = O_Wproj + (long)l * 7 * D2 +
           ((j==0) ? 0L : (j==1) ? 5L*D2 : 6L*D2);
    R = DD; C = DD;
  } else if (bid < 5632){                  // cross K/V: (l, ci, kv)
    const int idx = (bid - 1536) >> 8; rem = bid & 255;
    const int l = idx >> 3, ci = (idx >> 1) & 3, kv = idx & 1;
    src = kv ? Wv : Wk;
    soff = (long)(l*5 + 1 + ci) * D2;
    doff = O_WkvC + (long)(l*8 + ci*2 + kv) * D2;
    R = DD; C = DD;
  } else if (bid < 7680){                  // cross Q: (l, ci) -> slot 1+ci
    const int idx = (bid - 5632) >> 8; rem = bid & 255;
    const int l = idx >> 2, ci = idx & 3;
    src = Wq;
    soff = (long)(l*5 + 1 + ci) * D2;
    doff = O_Wproj + (long)l * 7 * D2 + (long)(1 + ci) * D2;
    R = DD; C = DD;
  } else if (bid < 10240){                 // Wo (10 matrices)
    const int idx = (bid - 7680) >> 8; rem = bid & 255;
    src = Wo; soff = (long)idx * D2; doff = O_WoT + (long)idx * D2;
    R = DD; C = DD;
  } else if (bid < 12288){                 // W1 [DD][FF], z=2
    const int b5 = bid - 10240;
    const int z = b5 >> 10; rem = b5 & 1023;
    src = W1; soff = (long)z * DF; doff = O_W1T + (long)z * DF;
    R = DD; C = FF;
  } else {                                 // W2 [FF][DD], z=2
    const int b6 = bid - 12288;
    const int z = b6 >> 10; rem = b6 & 1023;
    src = W2; soff = (long)z * DF; doff = O_W2T + (long)z * DF;
    R = FF; C = DD;
  }
  const int ctiles = C >> 6;
  const int c0 = (rem % ctiles) << 6;
  const int r0 = (rem / ctiles) << 6;

  __shared__ u16 tile[64][66];
  const int tr = tid >> 4, tc = tid & 15;
  #pragma unroll
  for (int i = 0; i < 4; ++i){
    const int row = tr + i*16;
    float4 v = ((const float4*)(src + soff + (long)(r0 + row)*C + c0))[tc];
    unsigned* t32 = (unsigned*)&tile[row][tc*4];
    t32[0] = (unsigned)f2bf(v.x) | ((unsigned)f2bf(v.y) << 16);
    t32[1] = (unsigned)f2bf(v.z) | ((unsigned)f2bf(v.w) << 16);
  }
  __syncthreads();
  const int ch = tid & 7;
  const int cb = tid >> 3;                 // 0..31
  #pragma unroll
  for (int it = 0; it < 2; ++it){
    const int cc = cb + it*32;             // output row = source col
    union { int4 v; u16 u[8]; } P;
    #pragma unroll
    for (int j = 0; j < 8; ++j) P.u[j] = tile[ch*8 + j][cc];
    *(int4*)&dst0[doff + (long)(c0 + cc)*R + r0 + ch*8] = P.v;
  }
}

// ---------------------------------------------------------------------------
// Chained residual+LN: x = LN(...LN(LN(x + o0) + o1)... + o4), f32 registers.
// ---------------------------------------------------------------------------
__global__ __launch_bounds__(256) void ln_chain5(
    const float* __restrict__ o5, u16* __restrict__ xb)
{
  const int row = blockIdx.x;
  const int i = threadIdx.x;
  const int lane = i & 63, wid = i >> 6;
  __shared__ float red[4];
  constexpr long NB = (long)2048 * 1024;
  ushort4 x4 = ((const ushort4*)(xb + (long)row * DD))[i];
  float4 x;
  x.x = bf2f(x4.x); x.y = bf2f(x4.y); x.z = bf2f(x4.z); x.w = bf2f(x4.w);
  #pragma unroll
  for (int it = 0; it < 5; ++it){
    float4 o = ((const float4*)(o5 + (long)it * NB + (long)row * DD))[i];
    x.x += o.x; x.y += o.y; x.z += o.z; x.w += o.w;
    float s = x.x + x.y + x.z + x.w;
    #pragma unroll
    for (int off = 32; off; off >>= 1) s += __shfl_xor(s, off);
    if (lane == 0) red[wid] = s;
    __syncthreads();
    const float mean = (red[0] + red[1] + red[2] + red[3]) * (1.0f / DD);
    __syncthreads();
    x.x -= mean; x.y -= mean; x.z -= mean; x.w -= mean;
    float q = x.x*x.x + x.y*x.y + x.z*x.z + x.w*x.w;
    #pragma unroll
    for (int off = 32; off; off >>= 1) q += __shfl_xor(q, off);
    if (lane == 0) red[wid] = q;
    __syncthreads();
    const float var = (red[0] + red[1] + red[2] + red[3]) * (1.0f / DD);
    const float rstd = rsqrtf(var + 1e-5f);
    x.x *= rstd; x.y *= rstd; x.z *= rstd; x.w *= rstd;
    __syncthreads();
  }
  ushort4 o4;
  o4.x = f2bf(x.x); o4.y = f2bf(x.y); o4.z = f2bf(x.z); o4.w = f2bf(x.w);
  ((ushort4*)(xb + (long)row * DD))[i] = o4;
}

// ---------------------------------------------------------------------------
// LayerNorm(a) -> yf (f32, optional) and yb (bf16, optional)
// ---------------------------------------------------------------------------
__global__ __launch_bounds__(256) void ln_kernel(
    const float* __restrict__ a,
    float* __restrict__ yf, u16* __restrict__ yb)
{
  const int row = blockIdx.x;
  const int i = threadIdx.x;
  const int lane = i & 63, wid = i >> 6;
  float4 x = ((const float4*)(a + (long)row * DD))[i];
  float s = x.x + x.y + x.z + x.w;
  #pragma unroll
  for (int o = 32; o; o >>= 1) s += __shfl_xor(s, o);
  __shared__ float red[4];
  if (lane == 0) red[wid] = s;
  __syncthreads();
  const float mean = (red[0] + red[1] + red[2] + red[3]) * (1.0f / DD);
  __syncthreads();
  const float dx = x.x - mean, dy = x.y - mean, dz = x.z - mean, dw = x.w - mean;
  float q = dx*dx + dy*dy + dz*dz + dw*dw;
  #pragma unroll
  for (int o = 32; o; o >>= 1) q += __shfl_xor(q, o);
  if (lane == 0) red[wid] = q;
  __syncthreads();
  const float var = (red[0] + red[1] + red[2] + red[3]) * (1.0f / DD);
  const float rstd = rsqrtf(var + 1e-5f);
  float4 y; y.x = dx*rstd; y.y = dy*rstd; y.z = dz*rstd; y.w = dw*rstd;
  if (yf) ((float4*)(yf + (long)row * DD))[i] = y;
  if (yb){
    ushort4 o4; o4.x = f2bf(y.x); o4.y = f2bf(y.y); o4.z = f2bf(y.z); o4.w = f2bf(y.w);
    ((ushort4*)(yb + (long)row * DD))[i] = o4;
  }
}

// ---------------------------------------------------------------------------
// Flash attention core (shared). T13 defer-max (THR=8).
// ---------------------------------------------------------------------------
template<bool CAUSAL>
__device__ __forceinline__ void flash_body(
    const u16* Q, const u16* Kt, const u16* Vt,
    const float* biasS, u16* O,
    int qt, int bh, u16 (*Ks)[64*64], u16 (*Vs)[64*64], u16* Ps)
{
  const int b = bh >> 4, h = bh & 15;
  const int tid = threadIdx.x, lane = tid & 63, wid = tid >> 6;
  const int fr = lane & 15, kg = lane >> 4;
  const int srow = tid >> 3;
  const int gcol = ((tid & 7) ^ (srow & 7)) * 8;
  u16* Pw = Ps + wid * 1024;
  const facc4 z4 = {0.0f, 0.0f, 0.0f, 0.0f};

  const long base = (long)bh * (512 * 64);
  const u16* qrow = Q + base + (long)(qt*64 + wid*16 + fr) * 64;
  const bfrag8 aq0 = *(const bfrag8*)(qrow + kg*8);
  const bfrag8 aq1 = *(const bfrag8*)(qrow + 32 + kg*8);

  auto stageKV = [&](int buf, int kt){
    u16* Kd = Ks[buf] + wid * 512;
    u16* Vd = Vs[buf] + wid * 512;
    #pragma unroll
    for (int p = 0; p < 2; ++p)
      gload16(Kt + base + (long)(kt*64 + p*32 + srow) * 64 + gcol, Kd + p*2048);
    #pragma unroll
    for (int p = 0; p < 2; ++p)
      gload16(Vt + base + (long)(p*32 + srow) * 512 + kt*64 + gcol, Vd + p*2048);
  };

  float mrow[4], lrow[4];
  #pragma unroll
  for (int r = 0; r < 4; ++r){ mrow[r] = -3e38f; lrow[r] = 0.0f; }
  facc4 accO[4] = {};

  const int NT = CAUSAL ? (qt + 1) : 8;
  stageKV(0, 0);
  if (NT > 1){ stageKV(1, 1); vwait<4>(); }
  else vwait<0>();
  __builtin_amdgcn_s_barrier();

  for (int kt = 0; kt < NT; ++kt){
    const int cur = kt & 1;
    bfrag8 bk[4][2], bv[4][2];
    #pragma unroll
    for (int j = 0; j < 4; ++j)
      #pragma unroll
      for (int c2 = 0; c2 < 2; ++c2){
        const int po = (((c2*4 + kg) ^ (fr & 7)) * 8);
        bk[j][c2] = *(const bfrag8*)&Ks[cur][(j*16 + fr)*64 + po];
        bv[j][c2] = *(const bfrag8*)&Vs[cur][(j*16 + fr)*64 + po];
      }
    __builtin_amdgcn_sched_barrier(0);
    __builtin_amdgcn_s_barrier();
    if (kt + 2 < NT){ stageKV(cur, kt + 2); vwait<4>(); }
    else vwait<0>();
    __builtin_amdgcn_s_barrier();

    // QK^T
    facc4 sc[4];
    __builtin_amdgcn_s_setprio(1);
    #pragma unroll
    for (int j = 0; j < 4; ++j){
      sc[j] = __builtin_amdgcn_mfma_f32_16x16x32_bf16(aq0, bk[j][0], z4, 0, 0, 0);
      sc[j] = __builtin_amdgcn_mfma_f32_16x16x32_bf16(aq1, bk[j][1], sc[j], 0, 0, 0);
    }
    __builtin_amdgcn_s_setprio(0);
    if (CAUSAL){
      const int rowb = qt*64 + wid*16 + kg*4;
      #pragma unroll
      for (int j = 0; j < 4; ++j){
        const int col = kt*64 + j*16 + fr;
        #pragma unroll
        for (int r = 0; r < 4; ++r)
          if (col > rowb + r) sc[j][r] = -1e20f;
      }
    } else {
      #pragma unroll
      for (int j = 0; j < 4; ++j){
        const float bval = biasS[kt*64 + j*16 + fr];
        #pragma unroll
        for (int r = 0; r < 4; ++r) sc[j][r] += bval;
      }
    }
    // online softmax with defer-max (T13, THR=8)
    float tmax[4];
    #pragma unroll
    for (int r = 0; r < 4; ++r)
      tmax[r] = fmaxf(fmaxf(sc[0][r], sc[1][r]), fmaxf(sc[2][r], sc[3][r]));
    #pragma unroll
    for (int o = 1; o < 16; o <<= 1)
      #pragma unroll
      for (int r = 0; r < 4; ++r)
        tmax[r] = fmaxf(tmax[r], __shfl_xor(tmax[r], o));
    bool grow = false;
    #pragma unroll
    for (int r = 0; r < 4; ++r) grow = grow || (tmax[r] > mrow[r] + 8.0f);
    if (__any(grow)){
      float fac[4];
      #pragma unroll
      for (int r = 0; r < 4; ++r){
        const float mn = fmaxf(mrow[r], tmax[r]);
        fac[r] = __expf(mrow[r] - mn);
        mrow[r] = mn;
        lrow[r] *= fac[r];
      }
      #pragma unroll
      for (int f = 0; f < 4; ++f)
        #pragma unroll
        for (int r = 0; r < 4; ++r) accO[f][r] *= fac[r];
    }
    float tsum[4] = {0.0f, 0.0f, 0.0f, 0.0f};
    #pragma unroll
    for (int j = 0; j < 4; ++j)
      #pragma unroll
      for (int r = 0; r < 4; ++r){
        const float p = __expf(sc[j][r] - mrow[r]);
        sc[j][r] = p; tsum[r] += p;
      }
    #pragma unroll
    for (int o = 1; o < 16; o <<= 1)
      #pragma unroll
      for (int r = 0; r < 4; ++r) tsum[r] += __shfl_xor(tsum[r], o);
    #pragma unroll
    for (int r = 0; r < 4; ++r) lrow[r] += tsum[r];

    // P -> wave-private LDS (chunk-swizzled), read back as A-frags
    #pragma unroll
    for (int j = 0; j < 4; ++j)
      #pragma unroll
      for (int r = 0; r < 4; ++r){
        const int row = kg*4 + r;
        const int col = j*16 + fr;
        Pw[row*64 + (((col >> 3) ^ (row & 7)) * 8) + (col & 7)] = f2bf(sc[j][r]);
      }
    bfrag8 ap[2];
    #pragma unroll
    for (int c2 = 0; c2 < 2; ++c2)
      ap[c2] = *(const bfrag8*)&Pw[fr*64 + (((c2*4 + kg) ^ (fr & 7)) * 8)];
    __builtin_amdgcn_s_setprio(1);
    #pragma unroll
    for (int f = 0; f < 4; ++f){
      accO[f] = __builtin_amdgcn_mfma_f32_16x16x32_bf16(ap[0], bv[f][0], accO[f], 0, 0, 0);
      accO[f] = __builtin_amdgcn_mfma_f32_16x16x32_bf16(ap[1], bv[f][1], accO[f], 0, 0, 0);
    }
    __builtin_amdgcn_s_setprio(0);
  }

  // epilogue: O/lrow via Pw bounce -> coalesced 16B stores
  #pragma unroll
  for (int f = 0; f < 4; ++f)
    #pragma unroll
    for (int r = 0; r < 4; ++r){
      const int row = kg*4 + r;
      const int col = f*16 + fr;
      Pw[(row*64 + col) ^ ((row & 7) << 3)] = f2bf(accO[f][r] / lrow[r]);
    }
  const int prow = lane >> 2, pch = lane & 3;
  const long orow = (long)(b*512 + qt*64 + wid*16 + prow) * 1024 + h*64;
  #pragma unroll
  for (int it2 = 0; it2 < 2; ++it2){
    const int ch2 = pch + it2*4;
    int4 w4 = *(const int4*)&Pw[(prow*64 + ch2*8) ^ ((prow & 7) << 3)];
    *(int4*)&O[orow + ch2*8] = w4;
  }
}

// ---- ALL 5 attentions in one launch, grid (8,64,5); z=0 self, z>=1 cross ----
__global__ __launch_bounds__(256, 3) void flash_all5(
    const u16* __restrict__ Qb5, const u16* __restrict__ Kb,
    const u16* __restrict__ Vtb, const u16* __restrict__ KVcl,
    const int* __restrict__ cmask, u16* __restrict__ O5)
{
  __shared__ __align__(16) u16 Ks[2][64*64];
  __shared__ __align__(16) u16 Vs[2][64*64];
  __shared__ __align__(16) u16 Ps[4*16*64];
  __shared__ float biasS[512];
  const int z = blockIdx.z;
  const int fid = blockIdx.y * 8 + blockIdx.x;
  const int lid = (fid & 7) * 64 + (fid >> 3);
  const int qt = lid & 7, bh = lid >> 3;
  constexpr long NB = (long)2048 * 1024;
  if (z == 0){
    flash_body<true>(Qb5, Kb, Vtb, nullptr, O5, qt, bh, Ks, Vs, Ps);
  } else {
    const int ci = z - 1;
    const int mode = (0x0312 >> (ci*4)) & 0xF;   // ci: 0->2, 1->1, 2->3, 3->0
    const int b = bh >> 4;
    const int tid = threadIdx.x;
    #pragma unroll
    for (int r = 0; r < 2; ++r){
      const int c = r * 256 + tid;
      biasS[c] = (cmask[b * 512 + c] != mode) ? 0.0f : -1e20f;
    }
    __syncthreads();
    flash_body<false>(Qb5 + (long)z * NB,
                      KVcl + (long)(ci*2) * NB, KVcl + (long)(ci*2 + 1) * NB,
                      biasS, O5 + (long)z * NB, qt, bh, Ks, Vs, Ps);
  }
}

// ---------------------------------------------------------------------------
#define MODE_F32   0
#define MODE_BF16  1
#define MODE_PROJ  6
#define MODE_F32B  7

__device__ __forceinline__ long qk_off(int gm, int gn){   // [b,h,t,d]
  return (((long)(gm >> 9) * HH + (gn >> 6)) * TT + (gm & (TT-1))) * DHH + (gn & (DHH-1));
}

// ---------------------------------------------------------------------------
// 8-phase 256x256 GEMM (guide's m201 template, plain HIP) for the KV
// precompute: C[z] = kvb[ci] x WkvC[z]^T + bias, z=16 batches, K=1024.
// 512 threads = 8 waves (2M x 4N), per-wave 128x64 output, BK=64,
// LDS 128KB = 2 dbuf x {A[2 half][128][64], B[2 half][128][64]} bf16.
// Schedule (derived + vmcnt-verified): stages buf0.{B0,B1,A0A1} at ph3/4/5
// (tile+2), buf1.{B0,B1A0A1} at ph7/8 (tile+3); vmcnt(4)@ph4 guarantees
// buf1 tile landed before ph5 reads; vmcnt(6)@ph8 guarantees buf0 tile+2
// landed before next ph1. Each stage targets a half whose reads completed
// >=1 barrier earlier. Final iteration: vwait<0>@ph4 (counted wait
// insufficient when stages are skipped).
// ---------------------------------------------------------------------------
__global__ __launch_bounds__(512, 2) void gemm256_kv(
    const u16* __restrict__ A, const u16* __restrict__ B,
    const float* __restrict__ bkb, const float* __restrict__ bvb,
    u16* __restrict__ Cb)
{
  __shared__ __align__(16) u16 lds[65536];     // 128 KB

  // XCD swizzle over 512 blocks
  const int gx = gridDim.x, gy = gridDim.y;
  const int nwg = gx * gy * gridDim.z;
  const int fid = (blockIdx.z * gy + blockIdx.y) * gx + blockIdx.x;
  const int cpx = nwg >> 3;
  const int lid = (fid & 7) * cpx + (fid >> 3);
  const int bx = lid % gx;
  const int rem = lid / gx;
  const int by = rem % gy;
  const int z  = rem / gy;

  constexpr long NBA = (long)2048 * 1024;
  constexpr long D2C = (long)DD * DD;
  const int ci = z >> 2, ll = (z >> 1) & 1, isv = z & 1;
  const u16* Ab = A + (long)ci * NBA;
  const u16* Bb = B + (long)(ll*8 + ci*2 + isv) * D2C;
  const long cbase = (long)(ll*8 + ci*2 + isv) * NBA;

  const int tid = threadIdx.x, lane = tid & 63, w = tid >> 6;
  const int m0 = by * 256, n0 = bx * 256;
  const int wmh = w >> 2;                  // A half (M 128-range)
  const int wn  = w & 3;                   // 64-col group
  const int bhf = wn >> 1;                 // B half
  const int brow0 = (wn & 1) * 64;         // row base within B half
  const int fr = lane & 15, kg = lane >> 4;
  facc4 acc[8][4] = {};

  const int sr8 = (tid >> 3) & 7;
  const int sgc = ((tid & 7) ^ sr8) * 8;   // pre-swizzled global chunk

  auto stageA = [&](int buf, int h, int t){
    u16* d = lds + (buf*2 + h) * 8192 + tid * 8;
    #pragma unroll
    for (int p = 0; p < 2; ++p)
      gload16(Ab + (long)(m0 + h*128 + p*64 + (tid >> 3)) * DD + t*64 + sgc,
              d + p*4096);
  };
  auto stageB = [&](int buf, int h, int t){
    u16* d = lds + 32768 + (buf*2 + h) * 8192 + tid * 8;
    #pragma unroll
    for (int p = 0; p < 2; ++p)
      gload16(Bb + (long)(n0 + h*128 + p*64 + (tid >> 3)) * DD + t*64 + sgc,
              d + p*4096);
  };

  bfrag8 af[4][2], bf[4][2];
  auto readA = [&](int buf, int mg){
    const u16* Ah = lds + (buf*2 + wmh) * 8192;
    #pragma unroll
    for (int q = 0; q < 4; ++q){
      const int row = (mg*4 + q)*16 + fr;
      #pragma unroll
      for (int c2 = 0; c2 < 2; ++c2)
        af[q][c2] = *(const bfrag8*)&Ah[row*64 + (((c2*4 + kg) ^ (fr & 7)) * 8)];
    }
  };
  auto readB = [&](int buf, int ng){
    const u16* Bh = lds + 32768 + (buf*2 + bhf) * 8192;
    #pragma unroll
    for (int q = 0; q < 2; ++q){
      const int row = brow0 + (ng*2 + q)*16 + fr;
      #pragma unroll
      for (int c2 = 0; c2 < 2; ++c2)
        bf[ng*2 + q][c2] = *(const bfrag8*)&Bh[row*64 + (((c2*4 + kg) ^ (fr & 7)) * 8)];
    }
  };
  auto mmaQ = [&](int mg, int ng){
    __builtin_amdgcn_s_setprio(1);
    #pragma unroll
    for (int q = 0; q < 4; ++q)
      #pragma unroll
      for (int r2 = 0; r2 < 2; ++r2){
        const int i = mg*4 + q, j = ng*2 + r2;
        acc[i][j] = __builtin_amdgcn_mfma_f32_16x16x32_bf16(af[q][0], bf[j][0], acc[i][j], 0, 0, 0);
        acc[i][j] = __builtin_amdgcn_mfma_f32_16x16x32_bf16(af[q][1], bf[j][1], acc[i][j], 0, 0, 0);
      }
    __builtin_amdgcn_s_setprio(0);
  };

  // prologue: tiles 0 (buf0) and 1 (buf1) fully staged
  stageB(0,0,0); stageB(0,1,0); stageA(0,0,0); stageA(0,1,0);
  stageB(1,0,1); stageB(1,1,1); stageA(1,0,1); stageA(1,1,1);
  vwait<8>();                              // buf0[0] landed
  __builtin_amdgcn_s_barrier();

  for (int J = 0; J < 8; ++J){
    const int t2 = 2*J + 2, t3 = 2*J + 3;
    const bool pf = (J < 7);
    // ph1: tile a=(2J) quadrant (0,0)
    readA(0, 0); readB(0, 0);
    __builtin_amdgcn_sched_barrier(0);
    __builtin_amdgcn_s_barrier();
    mmaQ(0, 0);
    __builtin_amdgcn_s_barrier();
    // ph2: (0,1)
    readB(0, 1);
    __builtin_amdgcn_sched_barrier(0);
    __builtin_amdgcn_s_barrier();
    mmaQ(0, 1);
    __builtin_amdgcn_s_barrier();
    // ph3: (1,0); stage buf0.B0[t2]
    readA(0, 1);
    if (pf) stageB(0, 0, t2);
    __builtin_amdgcn_sched_barrier(0);
    __builtin_amdgcn_s_barrier();
    mmaQ(1, 0);
    __builtin_amdgcn_s_barrier();
    // ph4: (1,1); stage buf0.B1[t2]; counted wait -> buf1[b] landed
    if (pf){ stageB(0, 1, t2); vwait<4>(); }
    else vwait<0>();
    __builtin_amdgcn_s_barrier();
    mmaQ(1, 1);
    __builtin_amdgcn_s_barrier();
    // ph5: tile b=(2J+1) quadrant (0,0); stage buf0.A0+A1[t2]
    readA(1, 0); readB(1, 0);
    if (pf){ stageA(0, 0, t2); stageA(0, 1, t2); }
    __builtin_amdgcn_sched_barrier(0);
    __builtin_amdgcn_s_barrier();
    mmaQ(0, 0);
    __builtin_amdgcn_s_barrier();
    // ph6: (0,1)
    readB(1, 1);
    __builtin_amdgcn_sched_barrier(0);
    __builtin_amdgcn_s_barrier();
    mmaQ(0, 1);
    __builtin_amdgcn_s_barrier();
    // ph7: (1,0); stage buf1.B0[t3]
    readA(1, 1);
    if (pf) stageB(1, 0, t3);
    __builtin_amdgcn_sched_barrier(0);
    __builtin_amdgcn_s_barrier();
    mmaQ(1, 0);
    __builtin_amdgcn_s_barrier();
    // ph8: (1,1); stage buf1.{B1,A0,A1}[t3]; counted wait -> buf0[t2] landed
    if (pf){ stageB(1, 1, t3); stageA(1, 0, t3); stageA(1, 1, t3); }
    vwait<6>();
    __builtin_amdgcn_s_barrier();
    mmaQ(1, 1);
    __builtin_amdgcn_s_barrier();
  }
  __syncthreads();

  // ---- epilogue: bounce through LDS (reuses full 128KB) ----
  u16* S = lds;
  if (isv){                                // V: transpose to [b,h,d,t]
    const float* vb = bvb + (long)(ll*5 + ci + 1) * DD;
    #pragma unroll
    for (int j = 0; j < 4; ++j){
      const int nl = wn*64 + j*16 + fr;
      const float bvv = vb[n0 + nl];
      #pragma unroll
      for (int i = 0; i < 8; ++i)
        #pragma unroll
        for (int rr = 0; rr < 4; ++rr){
          const int ml = wmh*128 + i*16 + kg*4 + rr;
          S[(nl*256 + ml) ^ ((nl & 7) << 3)] = f2bf(acc[i][j][rr] + bvv);
        }
    }
    __syncthreads();
    const int n = tid >> 1;                // 0..255
    const int mh = (tid & 1) * 128;
    const long rowoff = (((long)(m0 >> 9) * HH + ((n0 + n) >> 6)) * DHH
                         + ((n0 + n) & 63)) * TT + (m0 & 511) + mh;
    u16* vdst = Cb + cbase;
    #pragma unroll
    for (int c = 0; c < 16; ++c){
      int4 w4 = *(const int4*)&S[(n*256 + mh + c*8) ^ ((n & 7) << 3)];
      *(int4*)&vdst[rowoff + c*8] = w4;
    }
  } else {                                 // K: row-major [b,h,t,d]
    const float* bp = bkb + (long)(ll*5 + ci + 1) * DD;
    #pragma unroll
    for (int i = 0; i < 8; ++i)
      #pragma unroll
      for (int j = 0; j < 4; ++j){
        const int nl = wn*64 + j*16 + fr;
        const float bvv = bp[n0 + nl];
        #pragma unroll
        for (int rr = 0; rr < 4; ++rr){
          const int ml = wmh*128 + i*16 + kg*4 + rr;
          S[(ml*256 + nl) ^ ((ml & 7) << 3)] = f2bf(acc[i][j][rr] + bvv);
        }
      }
    __syncthreads();
    #pragma unroll
    for (int it = 0; it < 16; ++it){
      const int idx = it * 512 + tid;
      const int row = idx >> 5, ch = idx & 31;
      int4 w4 = *(const int4*)&S[(row*256 + ch*8) ^ ((row & 7) << 3)];
      *(int4*)&Cb[cbase + qk_off(m0 + row, n0 + ch*8)] = w4;
    }
  }
}

// ---------------------------------------------------------------------------
// 256-thread bf16 MFMA GEMM, BK=64, counted-vmcnt pipeline, XCD swizzle.
// NBUF=3 for 64x64 tiles; 2 otherwise. 128x128: 32 MFMA : 16 ds_read/step.
// ---------------------------------------------------------------------------
template<int BM, int BN, int MODE>
__global__ __launch_bounds__(256, 2) void gemm_k(
    const u16* __restrict__ A, const u16* __restrict__ B,
    const float* __restrict__ bias0, const float* __restrict__ bias1,
    const float* __restrict__ bias2,
    float* __restrict__ Cf, u16* __restrict__ Cb0, u16* __restrict__ Cb1,
    u16* __restrict__ Cb2, const u16* __restrict__ resb,
    int K, int lda, int ldb, int ldc,
    int relu, float alpha)
{
  constexpr int BK = 64;
  constexpr int NBUF = (BM == 64 && BN == 64) ? 3 : 2;
  constexpr int ASZ = BM * BK, BSZ = BN * BK;
  __shared__ __align__(16) u16 As[NBUF * ASZ];
  __shared__ __align__(16) u16 Bs[NBUF * BSZ];

  const int gx = gridDim.x, gy = gridDim.y;
  const int nwg = gx * gy * gridDim.z;
  const int fid = (blockIdx.z * gy + blockIdx.y) * gx + blockIdx.x;
  const int cpx = nwg >> 3;
  const int lid = (fid & 7) * cpx + (fid >> 3);
  const int bx = lid % gx;
  const int rem = lid / gx;
  const int by = rem % gy;
  const int z  = rem / gy;

  const u16* Ab;
  const u16* Bb;
  long cbase;
  constexpr long NBA = (long)2048 * 1024;
  constexpr long D2C = (long)DD * DD;
  if constexpr (MODE == MODE_F32B){
    Ab = A + (long)z * NBA;
    Bb = B + (long)z * D2C;
    cbase = (long)z * NBA;
  } else {
    Ab = A; Bb = B; cbase = 0;
  }
  const int tid = threadIdx.x, lane = tid & 63, wid = tid >> 6;
  const int m0 = by * BM, n0 = bx * BN;
  constexpr int TMW = BM / 2, TNW = BN / 2;           // 2x2 wave grid
  constexpr int FM = TMW / 16, FN = TNW / 16;
  const int wm = (wid >> 1) * TMW, wn = (wid & 1) * TNW;
  const int fr = lane & 15, kg = lane >> 4;
  facc4 acc[FM][FN] = {};

  const int srow = tid >> 3;
  const int gcol = (((tid & 7) ^ (srow & 7)) * 8);
  constexpr int AP = BM / 32, BP = BN / 32;
  constexpr int LPS = AP + BP;

  auto stage = [&](int buf, int k0){
    u16* Ad = As + buf * ASZ + wid * 512;
    u16* Bd = Bs + buf * BSZ + wid * 512;
    #pragma unroll
    for (int p = 0; p < AP; ++p)
      gload16(Ab + (long)(m0 + p*32 + srow) * lda + (k0 + gcol), Ad + p*2048);
    #pragma unroll
    for (int p = 0; p < BP; ++p)
      gload16(Bb + (long)(n0 + p*32 + srow) * ldb + (k0 + gcol), Bd + p*2048);
  };

  const int nsteps = K / BK;
  stage(0, 0);
  if constexpr (NBUF == 3){
    if (nsteps > 1) stage(1, BK);
    if (nsteps > 2) stage(2, 2*BK);
    if (nsteps > 2) vwait<2*LPS>();
    else if (nsteps > 1) vwait<LPS>();
    else vwait<0>();
  } else {
    if (nsteps > 1){ stage(1, BK); vwait<LPS>(); }
    else vwait<0>();
  }
  __builtin_amdgcn_s_barrier();

  int cur = 0;
  for (int s = 0; s < nsteps; ++s){
    const u16* Ar = As + cur * ASZ;
    const u16* Br = Bs + cur * BSZ;
    bfrag8 af[FM][2], bfv[FN][2];
    #pragma unroll
    for (int i = 0; i < FM; ++i)
      #pragma unroll
      for (int c2 = 0; c2 < 2; ++c2)
        af[i][c2] = *(const bfrag8*)&Ar[(wm + i*16 + fr) * 64 + (((c2*4 + kg) ^ (fr & 7)) * 8)];
    #pragma unroll
    for (int j = 0; j < FN; ++j)
      #pragma unroll
      for (int c2 = 0; c2 < 2; ++c2)
        bfv[j][c2] = *(const bfrag8*)&Br[(wn + j*16 + fr) * 64 + (((c2*4 + kg) ^ (fr & 7)) * 8)];
    __builtin_amdgcn_sched_barrier(0);
    __builtin_amdgcn_s_barrier();
    if constexpr (NBUF == 3){
      if (s + 3 < nsteps){ stage(cur, (s + 3) * BK); vwait<2*LPS>(); }
      else if (s + 2 < nsteps) vwait<LPS>();
      else if (s + 1 < nsteps) vwait<0>();
    } else {
      if (s + 2 < nsteps){ stage(cur, (s + 2) * BK); vwait<LPS>(); }
      else if (s + 1 < nsteps) vwait<0>();
    }
    __builtin_amdgcn_s_barrier();
    #pragma unroll
    for (int i = 0; i < FM; ++i)
      #pragma unroll
      for (int j = 0; j < FN; ++j){
        acc[i][j] = __builtin_amdgcn_mfma_f32_16x16x32_bf16(af[i][0], bfv[j][0], acc[i][j], 0, 0, 0);
        acc[i][j] = __builtin_amdgcn_mfma_f32_16x16x32_bf16(af[i][1], bfv[j][1], acc[i][j], 0, 0, 0);
      }
    cur = (cur == NBUF - 1) ? 0 : cur + 1;
  }

  // ---- V^T output path (PROJ V_self section): LDS transpose bounce ----
  if constexpr (MODE == MODE_PROJ){
    if ((n0 >> 10) == 6){
      const float* vb = bias2;
      u16* vdst = Cb2;
      const int n0e = n0 - 6144;
      u16* S = Bs;
      #pragma unroll
      for (int j = 0; j < FN; ++j){
        const int nl = wn + j*16 + fr;
        const float bvv = vb[n0e + nl];
        #pragma unroll
        for (int i = 0; i < FM; ++i)
          #pragma unroll
          for (int rr = 0; rr < 4; ++rr){
            const int ml = wm + i*16 + kg*4 + rr;
            S[(nl*BM + ml) ^ ((nl & 7) << 3)] = f2bf(acc[i][j][rr] + bvv);
          }
      }
      __syncthreads();
      constexpr int TPR = 256 / BN;
      constexpr int CPT = BM / (8 * TPR);
      const int n = tid / TPR;
      const int mh = (tid % TPR) * (BM / TPR);
      const long rowoff = (((long)(m0 >> 9) * HH + ((n0e + n) >> 6)) * DHH
                           + ((n0e + n) & 63)) * TT + (m0 & 511) + mh;
      #pragma unroll
      for (int c = 0; c < CPT; ++c){
        int4 w4 = *(const int4*)&S[(n*BM + mh + c*8) ^ ((n & 7) << 3)];
        *(int4*)&vdst[rowoff + c*8] = w4;
      }
      return;
    }
  }

  // ---- bf16 row-major bounce (MODE_BF16 / PROJ Q,K) ----
  if constexpr (MODE == MODE_BF16 || MODE == MODE_PROJ){
    u16* S = As;                 // NBUF*ASZ u16 >= BM*BN u16 for all configs
    const float* bp = bias0;
    float sc2 = alpha;
    u16* dst = Cb0;
    int nb = 0;
    constexpr long NBA2 = (long)2048 * 1024;
    if constexpr (MODE == MODE_PROJ){
      const int sect = n0 >> 10;           // 0..5 here (128 | 1024 -> no straddle)
      nb = n0 & 1023;
      if (sect <= 4){ bp = bias0 + (long)sect * DD; sc2 = 0.125f; dst = Cb0 + (long)sect * NBA2; }
      else          { bp = bias1; sc2 = 1.0f; dst = Cb1; }
    }
    #pragma unroll
    for (int i = 0; i < FM; ++i)
      #pragma unroll
      for (int j = 0; j < FN; ++j){
        const int nl = wn + j*16 + fr;
        float bvv;
        if constexpr (MODE == MODE_PROJ) bvv = bp[nb + nl];
        else bvv = bp ? bp[n0 + nl] : 0.0f;
        #pragma unroll
        for (int rr = 0; rr < 4; ++rr){
          const int ml = wm + i*16 + kg*4 + rr;
          float v = (acc[i][j][rr] + bvv) * sc2;
          if (relu) v = fmaxf(v, 0.0f);
          S[(ml*BN + nl) ^ ((ml & 7) << 3)] = f2bf(v);
        }
      }
    __syncthreads();
    constexpr int CPR = BN / 8;                 // 16B chunks per row
    constexpr int NIT = (BM * CPR) / 256;
    #pragma unroll
    for (int it = 0; it < NIT; ++it){
      const int idx = it * 256 + tid;
      const int row = idx / CPR, ch = idx % CPR;
      int4 w4 = *(const int4*)&S[(row*BN + ch*8) ^ ((row & 7) << 3)];
      const int gm = m0 + row;
      long off;
      if constexpr (MODE == MODE_BF16) off = cbase + (long)gm * ldc + (n0 + ch*8);
      else off = qk_off(gm, nb + ch*8);
      *(int4*)&dst[off] = w4;
    }
    return;
  }

  // Epilogue (MODE_F32 / MODE_F32B). C/D layout: col = fr, row = kg*4 + rr.
  {
    const float* bp0 = bias0;
    if constexpr (MODE == MODE_F32B) bp0 = bias0 + (long)z * DD;
    #pragma unroll
    for (int i = 0; i < FM; ++i){
      #pragma unroll
      for (int j = 0; j < FN; ++j){
        const int gn = n0 + wn + j*16 + fr;
        #pragma unroll
        for (int rr = 0; rr < 4; ++rr){
          const int gm = m0 + wm + i*16 + kg*4 + rr;
          float v = acc[i][j][rr];
          v = (v + (bp0 ? bp0[gn] : 0.0f)) * alpha;
          if (relu) v = fmaxf(v, 0.0f);
          const long off = cbase + (long)gm * ldc + gn;
          if constexpr (MODE == MODE_F32){
            if (resb) v += bf2f(resb[off]);        // fused bf16 residual
          }
          Cf[off] = v;
        }
      }
    }
  }
}

// ---------------------------------------------------------------------------
extern "C" void kernel_launch(void* const* d_in, const int* in_sizes, int n_in,
                              void* d_out, int out_size, void* d_ws, size_t ws_size,
                              hipStream_t stream)
{
  (void)in_sizes; (void)n_in; (void)out_size; (void)ws_size;
  const float* emb   = (const float*)d_in[0];
  const int*   pvec  = (const int*)d_in[1];
  const float* g_enc = (const float*)d_in[2];
  const float* g_con = (const float*)d_in[3];
  const float* g_db  = (const float*)d_in[4];
  const float* g_usr = (const float*)d_in[5];
  const int*   cmask = (const int*)d_in[6];
  const float* pose  = (const float*)d_in[7];
  const float* Wq = (const float*)d_in[8];
  const float* bq = (const float*)d_in[9];
  const float* Wk = (const float*)d_in[10];
  const float* bk = (const float*)d_in[11];
  const float* Wv = (const float*)d_in[12];
  const float* bv = (const float*)d_in[13];
  const float* Wo = (const float*)d_in[14];
  const float* bo = (const float*)d_in[15];
  const float* W1 = (const float*)d_in[16];
  const float* b1 = (const float*)d_in[17];
  const float* W2 = (const float*)d_in[18];
  const float* b2 = (const float*)d_in[19];
  float* out = (float*)d_out;

  const size_t NTOK = (size_t)BB * TT;   // 2048
  const long D2 = (long)DD * DD;

  char* wp = (char*)d_ws;
  auto alloc = [&](size_t bytes) -> char* {
    char* p = wp;
    wp += (bytes + 255) & ~(size_t)255;
    return p;
  };
  // NOTE: the first 5 arrays' order/offsets are hard-coded in prep_all.
  u16*   WprojT = (u16*) alloc(sizeof(u16) * 2 * 7 * D2);   // [l][7 slots]
  u16*   WkvC   = (u16*) alloc(sizeof(u16) * 2 * 4 * 2 * D2);
  u16*   WoT    = (u16*) alloc(sizeof(u16) * 10 * D2);
  u16*   W1T    = (u16*) alloc(sizeof(u16) * 2 * DD * FF);
  u16*   W2T    = (u16*) alloc(sizeof(u16) * 2 * DD * FF);
  // kvb0..3 MUST stay contiguous: gemm256_kv indexes them as [4][NTOK][DD]
  u16*   kvb0  = (u16*)  alloc(sizeof(u16) * NTOK * DD);
  u16*   kvb1  = (u16*)  alloc(sizeof(u16) * NTOK * DD);
  u16*   kvb2  = (u16*)  alloc(sizeof(u16) * NTOK * DD);
  u16*   kvb3  = (u16*)  alloc(sizeof(u16) * NTOK * DD);
  u16*   KVc   = (u16*)  alloc(sizeof(u16) * 16 * NTOK * DD);
  u16*   xb    = (u16*)  alloc(sizeof(u16) * NTOK * DD);
  u16*   Qb5   = (u16*)  alloc(sizeof(u16) * 5 * NTOK * DD);
  u16*   Kb    = (u16*)  alloc(sizeof(u16) * NTOK * DD);
  u16*   Vtb   = (u16*)  alloc(sizeof(u16) * NTOK * DD);
  u16*   attnb5= (u16*)  alloc(sizeof(u16) * 5 * NTOK * DD);
  float* oproj5= (float*)alloc(sizeof(float) * 5 * NTOK * DD);
  float* obuf  = (float*)alloc(sizeof(float) * NTOK * DD);
  u16*   hb    = (u16*)  alloc(sizeof(u16) * NTOK * FF);

  // ---- ONE prep launch: transposes + kv converts + embed/LN ----
  prep_all<<<24576, 256, 0, stream>>>(
      Wq, Wk, Wv, Wo, W1, W2, g_db, g_con, g_usr, g_enc,
      (u16*)d_ws, kvb0, kvb1, kvb2, kvb3,
      emb, pvec, pose, xb);

  // ---- all cross-attention K/V: 8-phase 256^2 template, 512 blocks ----
  const long NB = (long)NTOK * DD;
  gemm256_kv<<<dim3(4,8,16), 512, 0, stream>>>(kvb0, WkvC, bk, bv, KVc);

  for (int l = 0; l < 2; ++l){
    // ---- batched projections: [Q x5 | K_self | V_self], N = 7168 ----
    gemm_k<128,128,MODE_PROJ><<<dim3(56,16,1), 256, 0, stream>>>(
      xb, WprojT + (long)l*7*D2,
      bq + (size_t)l*5*DD, bk + (size_t)l*5*DD, bv + (size_t)l*5*DD,
      nullptr, Qb5, Kb, Vtb, nullptr,
      DD, DD, DD, 0, 0, 1.0f);

    // ALL 5 attentions (self causal + 4 cross) in one launch
    flash_all5<<<dim3(8,64,5), 256, 0, stream>>>(
        Qb5, Kb, Vtb, KVc + (long)l*8*NB, cmask, attnb5);

    // ALL 5 O-projections batched (z = i), f32 out, 128x128 tiles
    gemm_k<128,128,MODE_F32B><<<dim3(8,16,5), 256, 0, stream>>>(
      attnb5, WoT + (long)l*5*D2,
      bo + (size_t)l*5*DD, nullptr, nullptr,
      oproj5, nullptr, nullptr, nullptr, nullptr,
      DD, DD, DD, DD, 0, 1.0f);

    // chained residual+LN (one launch, f32 registers across 5 steps)
    ln_chain5<<<(int)NTOK, 256, 0, stream>>>(oproj5, xb);

    // FFN
    gemm_k<128,128,MODE_BF16><<<dim3(32,16,1), 256, 0, stream>>>(
      xb, W1T + (size_t)l*DD*FF,
      b1 + (size_t)l*FF, nullptr, nullptr,
      nullptr, hb, nullptr, nullptr, nullptr,
      DD, DD, DD, FF, 1, 1.0f);
    gemm_k<64,64,MODE_F32><<<dim3(16,32,1), 256, 0, stream>>>(
      hb, W2T + (size_t)l*DD*FF,
      b2 + (size_t)l*DD, nullptr, nullptr,
      obuf, nullptr, nullptr, nullptr, xb,
      FF, FF, FF, DD, 0, 1.0f);
    float* yf = (l == 1) ? out : nullptr;
    ln_kernel<<<(int)NTOK, 256, 0, stream>>>(obuf, yf, (l == 1) ? nullptr : xb);
  }
}

// Round 26
// 670.120 us; speedup vs baseline: 1.0302x; 1.0036x over previous
//
#include <hip/hip_runtime.h>

// Problem constants (Bert4KGModel): B=4, T=S=512, D=1024, H=16, dh=64, F=4096, L=2
#define BB  4
#define TT  512
#define DD  1024
#define HH  16
#define DHH 64
#define FF  4096

typedef unsigned short u16;
typedef __attribute__((ext_vector_type(8))) short bfrag8;   // 8 bf16 (4 VGPRs)
typedef __attribute__((ext_vector_type(4))) float facc4;    // 4 f32 acc

__device__ __forceinline__ u16 f2bf(float f){
  unsigned u = __float_as_uint(f);
  unsigned r = u + 0x7fffu + ((u >> 16) & 1u);   // RNE
  return (u16)(r >> 16);
}
__device__ __forceinline__ float bf2f(u16 h){
  return __uint_as_float(((unsigned)h) << 16);
}

// async global->LDS, 16B per lane; LDS dest is wave-uniform base + lane*16
__device__ __forceinline__ void gload16(const u16* g, u16* l){
  __builtin_amdgcn_global_load_lds(
      (const __attribute__((address_space(1))) void*)g,
      (__attribute__((address_space(3))) void*)l, 16, 0, 0);
}

// counted vmcnt wait (literal immediates only)
template<int N> __device__ __forceinline__ void vwait(){
  static_assert(N==0 || N==4 || N==6 || N==8 || N==12, "bad vmcnt literal");
  if constexpr (N==0)  asm volatile("s_waitcnt vmcnt(0)" ::: "memory");
  else if constexpr (N==4)  asm volatile("s_waitcnt vmcnt(4)" ::: "memory");
  else if constexpr (N==6)  asm volatile("s_waitcnt vmcnt(6)" ::: "memory");
  else if constexpr (N==8)  asm volatile("s_waitcnt vmcnt(8)" ::: "memory");
  else if constexpr (N==12) asm volatile("s_waitcnt vmcnt(12)" ::: "memory");
}

// ---------------------------------------------------------------------------
// ONE prep launch (64x64 tiles, full-128B-line packed stores) + kv converts
// + fused embed+LN tail blocks. Transpose-range XCD swizzle (kept, ~neutral).
// Blocks [0,14336): transposes. [14336,22528): converts. [22528,24576): embed.
// prep is at its practical floor (~107us) after r9/r12/r19/r22 experiments.
// ---------------------------------------------------------------------------
__global__ __launch_bounds__(256) void prep_all(
    const float* __restrict__ Wq, const float* __restrict__ Wk,
    const float* __restrict__ Wv, const float* __restrict__ Wo,
    const float* __restrict__ W1, const float* __restrict__ W2,
    const float* __restrict__ g_db, const float* __restrict__ g_con,
    const float* __restrict__ g_usr, const float* __restrict__ g_enc,
    u16* __restrict__ dst0,
    u16* __restrict__ kvb0, u16* __restrict__ kvb1,
    u16* __restrict__ kvb2, u16* __restrict__ kvb3,
    const float* __restrict__ emb, const int* __restrict__ pvec,
    const float* __restrict__ pos, u16* __restrict__ xbout)
{
  const int fid = blockIdx.x;
  const int bid = (fid < 14336) ? ((fid & 7) * 1792 + (fid >> 3)) : fid;
  const int tid = threadIdx.x;
  if (bid >= 22528){                       // ---- fused embed + LN ----
    const int row = bid - 22528;
    const int lane = tid & 63, wid = tid >> 6;
    const int idx = pvec[row];
    const int t = row & (TT - 1);
    float4 e = ((const float4*)(emb + (long)idx * DD))[tid];
    float4 p = ((const float4*)(pos + (long)t * DD))[tid];
    float4 x;
    x.x = e.x * 32.0f + p.x; x.y = e.y * 32.0f + p.y;
    x.z = e.z * 32.0f + p.z; x.w = e.w * 32.0f + p.w;
    float s = x.x + x.y + x.z + x.w;
    #pragma unroll
    for (int o = 32; o; o >>= 1) s += __shfl_xor(s, o);
    __shared__ float red[4];
    if (lane == 0) red[wid] = s;
    __syncthreads();
    const float mean = (red[0] + red[1] + red[2] + red[3]) * (1.0f / DD);
    __syncthreads();
    const float dx = x.x - mean, dy = x.y - mean, dz = x.z - mean, dw = x.w - mean;
    float q = dx*dx + dy*dy + dz*dz + dw*dw;
    #pragma unroll
    for (int o = 32; o; o >>= 1) q += __shfl_xor(q, o);
    if (lane == 0) red[wid] = q;
    __syncthreads();
    const float var = (red[0] + red[1] + red[2] + red[3]) * (1.0f / DD);
    const float rstd = rsqrtf(var + 1e-5f);
    ushort4 o4;
    o4.x = f2bf(dx*rstd); o4.y = f2bf(dy*rstd);
    o4.z = f2bf(dz*rstd); o4.w = f2bf(dw*rstd);
    ((ushort4*)(xbout + (long)row * DD))[tid] = o4;
    return;
  }
  if (bid >= 14336){                       // ---- kv convert ----
    const int r = bid - 14336;
    const float* s; u16* d;
    switch (r >> 11){
      case 0: s = g_db;  d = kvb0; break;
      case 1: s = g_con; d = kvb1; break;
      case 2: s = g_usr; d = kvb2; break;
      default: s = g_enc; d = kvb3; break;
    }
    const int i = (r & 2047) * 256 + tid;
    float4 v = ((const float4*)s)[i];
    ushort4 o;
    o.x = f2bf(v.x); o.y = f2bf(v.y); o.z = f2bf(v.z); o.w = f2bf(v.w);
    ((ushort4*)d)[i] = o;
    return;
  }
  constexpr long D2 = (long)DD * DD, DF = (long)DD * FF;
  constexpr long O_Wproj = 0, O_WkvC = 14*D2, O_WoT = 30*D2,
                 O_W1T = 40*D2, O_W2T = 40*D2 + 2*DF;
  const float* src; long soff, doff; int R, C, rem;
  if (bid < 1536){                         // self Wq/Wk/Wv (j) x layer (l)
    const int j = bid / 512;
    src = (j==0) ? Wq : (j==1) ? Wk : Wv;
    const int l = (bid % 512) / 256; rem = bid & 255;
    soff = (long)l * 5 * D2;
    doff = O_Wproj + (long)l * 7 * D2 +
           ((j==0) ? 0L : (j==1) ? 5L*D2 : 6L*D2);
    R = DD; C = DD;
  } else if (bid < 5632){                  // cross K/V: (l, ci, kv)
    const int idx = (bid - 1536) >> 8; rem = bid & 255;
    const int l = idx >> 3, ci = (idx >> 1) & 3, kv = idx & 1;
    src = kv ? Wv : Wk;
    soff = (long)(l*5 + 1 + ci) * D2;
    doff = O_WkvC + (long)(l*8 + ci*2 + kv) * D2;
    R = DD; C = DD;
  } else if (bid < 7680){                  // cross Q: (l, ci) -> slot 1+ci
    const int idx = (bid - 5632) >> 8; rem = bid & 255;
    const int l = idx >> 2, ci = idx & 3;
    src = Wq;
    soff = (long)(l*5 + 1 + ci) * D2;
    doff = O_Wproj + (long)l * 7 * D2 + (long)(1 + ci) * D2;
    R = DD; C = DD;
  } else if (bid < 10240){                 // Wo (10 matrices)
    const int idx = (bid - 7680) >> 8; rem = bid & 255;
    src = Wo; soff = (long)idx * D2; doff = O_WoT + (long)idx * D2;
    R = DD; C = DD;
  } else if (bid < 12288){                 // W1 [DD][FF], z=2
    const int b5 = bid - 10240;
    const int z = b5 >> 10; rem = b5 & 1023;
    src = W1; soff = (long)z * DF; doff = O_W1T + (long)z * DF;
    R = DD; C = FF;
  } else {                                 // W2 [FF][DD], z=2
    const int b6 = bid - 12288;
    const int z = b6 >> 10; rem = b6 & 1023;
    src = W2; soff = (long)z * DF; doff = O_W2T + (long)z * DF;
    R = FF; C = DD;
  }
  const int ctiles = C >> 6;
  const int c0 = (rem % ctiles) << 6;
  const int r0 = (rem / ctiles) << 6;

  __shared__ u16 tile[64][66];
  const int tr = tid >> 4, tc = tid & 15;
  #pragma unroll
  for (int i = 0; i < 4; ++i){
    const int row = tr + i*16;
    float4 v = ((const float4*)(src + soff + (long)(r0 + row)*C + c0))[tc];
    unsigned* t32 = (unsigned*)&tile[row][tc*4];
    t32[0] = (unsigned)f2bf(v.x) | ((unsigned)f2bf(v.y) << 16);
    t32[1] = (unsigned)f2bf(v.z) | ((unsigned)f2bf(v.w) << 16);
  }
  __syncthreads();
  const int ch = tid & 7;
  const int cb = tid >> 3;                 // 0..31
  #pragma unroll
  for (int it = 0; it < 2; ++it){
    const int cc = cb + it*32;             // output row = source col
    union { int4 v; u16 u[8]; } P;
    #pragma unroll
    for (int j = 0; j < 8; ++j) P.u[j] = tile[ch*8 + j][cc];
    *(int4*)&dst0[doff + (long)(c0 + cc)*R + r0 + ch*8] = P.v;
  }
}

// ---------------------------------------------------------------------------
// Chained residual+LN: x = LN(...LN(LN(x + o0) + o1)... + o4), f32 registers.
// ---------------------------------------------------------------------------
__global__ __launch_bounds__(256) void ln_chain5(
    const float* __restrict__ o5, u16* __restrict__ xb)
{
  const int row = blockIdx.x;
  const int i = threadIdx.x;
  const int lane = i & 63, wid = i >> 6;
  __shared__ float red[4];
  constexpr long NB = (long)2048 * 1024;
  ushort4 x4 = ((const ushort4*)(xb + (long)row * DD))[i];
  float4 x;
  x.x = bf2f(x4.x); x.y = bf2f(x4.y); x.z = bf2f(x4.z); x.w = bf2f(x4.w);
  #pragma unroll
  for (int it = 0; it < 5; ++it){
    float4 o = ((const float4*)(o5 + (long)it * NB + (long)row * DD))[i];
    x.x += o.x; x.y += o.y; x.z += o.z; x.w += o.w;
    float s = x.x + x.y + x.z + x.w;
    #pragma unroll
    for (int off = 32; off; off >>= 1) s += __shfl_xor(s, off);
    if (lane == 0) red[wid] = s;
    __syncthreads();
    const float mean = (red[0] + red[1] + red[2] + red[3]) * (1.0f / DD);
    __syncthreads();
    x.x -= mean; x.y -= mean; x.z -= mean; x.w -= mean;
    float q = x.x*x.x + x.y*x.y + x.z*x.z + x.w*x.w;
    #pragma unroll
    for (int off = 32; off; off >>= 1) q += __shfl_xor(q, off);
    if (lane == 0) red[wid] = q;
    __syncthreads();
    const float var = (red[0] + red[1] + red[2] + red[3]) * (1.0f / DD);
    const float rstd = rsqrtf(var + 1e-5f);
    x.x *= rstd; x.y *= rstd; x.z *= rstd; x.w *= rstd;
    __syncthreads();
  }
  ushort4 o4;
  o4.x = f2bf(x.x); o4.y = f2bf(x.y); o4.z = f2bf(x.z); o4.w = f2bf(x.w);
  ((ushort4*)(xb + (long)row * DD))[i] = o4;
}

// ---------------------------------------------------------------------------
// LayerNorm(a) -> yf (f32, optional) and yb (bf16, optional)
// ---------------------------------------------------------------------------
__global__ __launch_bounds__(256) void ln_kernel(
    const float* __restrict__ a,
    float* __restrict__ yf, u16* __restrict__ yb)
{
  const int row = blockIdx.x;
  const int i = threadIdx.x;
  const int lane = i & 63, wid = i >> 6;
  float4 x = ((const float4*)(a + (long)row * DD))[i];
  float s = x.x + x.y + x.z + x.w;
  #pragma unroll
  for (int o = 32; o; o >>= 1) s += __shfl_xor(s, o);
  __shared__ float red[4];
  if (lane == 0) red[wid] = s;
  __syncthreads();
  const float mean = (red[0] + red[1] + red[2] + red[3]) * (1.0f / DD);
  __syncthreads();
  const float dx = x.x - mean, dy = x.y - mean, dz = x.z - mean, dw = x.w - mean;
  float q = dx*dx + dy*dy + dz*dz + dw*dw;
  #pragma unroll
  for (int o = 32; o; o >>= 1) q += __shfl_xor(q, o);
  if (lane == 0) red[wid] = q;
  __syncthreads();
  const float var = (red[0] + red[1] + red[2] + red[3]) * (1.0f / DD);
  const float rstd = rsqrtf(var + 1e-5f);
  float4 y; y.x = dx*rstd; y.y = dy*rstd; y.z = dz*rstd; y.w = dw*rstd;
  if (yf) ((float4*)(yf + (long)row * DD))[i] = y;
  if (yb){
    ushort4 o4; o4.x = f2bf(y.x); o4.y = f2bf(y.y); o4.z = f2bf(y.z); o4.w = f2bf(y.w);
    ((ushort4*)(yb + (long)row * DD))[i] = o4;
  }
}

// ---------------------------------------------------------------------------
// Flash attention core (shared). T13 defer-max (THR=8).
// ---------------------------------------------------------------------------
template<bool CAUSAL>
__device__ __forceinline__ void flash_body(
    const u16* Q, const u16* Kt, const u16* Vt,
    const float* biasS, u16* O,
    int qt, int bh, u16 (*Ks)[64*64], u16 (*Vs)[64*64], u16* Ps)
{
  const int b = bh >> 4, h = bh & 15;
  const int tid = threadIdx.x, lane = tid & 63, wid = tid >> 6;
  const int fr = lane & 15, kg = lane >> 4;
  const int srow = tid >> 3;
  const int gcol = ((tid & 7) ^ (srow & 7)) * 8;
  u16* Pw = Ps + wid * 1024;
  const facc4 z4 = {0.0f, 0.0f, 0.0f, 0.0f};

  const long base = (long)bh * (512 * 64);
  const u16* qrow = Q + base + (long)(qt*64 + wid*16 + fr) * 64;
  const bfrag8 aq0 = *(const bfrag8*)(qrow + kg*8);
  const bfrag8 aq1 = *(const bfrag8*)(qrow + 32 + kg*8);

  auto stageKV = [&](int buf, int kt){
    u16* Kd = Ks[buf] + wid * 512;
    u16* Vd = Vs[buf] + wid * 512;
    #pragma unroll
    for (int p = 0; p < 2; ++p)
      gload16(Kt + base + (long)(kt*64 + p*32 + srow) * 64 + gcol, Kd + p*2048);
    #pragma unroll
    for (int p = 0; p < 2; ++p)
      gload16(Vt + base + (long)(p*32 + srow) * 512 + kt*64 + gcol, Vd + p*2048);
  };

  float mrow[4], lrow[4];
  #pragma unroll
  for (int r = 0; r < 4; ++r){ mrow[r] = -3e38f; lrow[r] = 0.0f; }
  facc4 accO[4] = {};

  const int NT = CAUSAL ? (qt + 1) : 8;
  stageKV(0, 0);
  if (NT > 1){ stageKV(1, 1); vwait<4>(); }
  else vwait<0>();
  __builtin_amdgcn_s_barrier();

  for (int kt = 0; kt < NT; ++kt){
    const int cur = kt & 1;
    bfrag8 bk[4][2], bv[4][2];
    #pragma unroll
    for (int j = 0; j < 4; ++j)
      #pragma unroll
      for (int c2 = 0; c2 < 2; ++c2){
        const int po = (((c2*4 + kg) ^ (fr & 7)) * 8);
        bk[j][c2] = *(const bfrag8*)&Ks[cur][(j*16 + fr)*64 + po];
        bv[j][c2] = *(const bfrag8*)&Vs[cur][(j*16 + fr)*64 + po];
      }
    __builtin_amdgcn_sched_barrier(0);
    __builtin_amdgcn_s_barrier();
    if (kt + 2 < NT){ stageKV(cur, kt + 2); vwait<4>(); }
    else vwait<0>();
    __builtin_amdgcn_s_barrier();

    // QK^T
    facc4 sc[4];
    __builtin_amdgcn_s_setprio(1);
    #pragma unroll
    for (int j = 0; j < 4; ++j){
      sc[j] = __builtin_amdgcn_mfma_f32_16x16x32_bf16(aq0, bk[j][0], z4, 0, 0, 0);
      sc[j] = __builtin_amdgcn_mfma_f32_16x16x32_bf16(aq1, bk[j][1], sc[j], 0, 0, 0);
    }
    __builtin_amdgcn_s_setprio(0);
    if (CAUSAL){
      const int rowb = qt*64 + wid*16 + kg*4;
      #pragma unroll
      for (int j = 0; j < 4; ++j){
        const int col = kt*64 + j*16 + fr;
        #pragma unroll
        for (int r = 0; r < 4; ++r)
          if (col > rowb + r) sc[j][r] = -1e20f;
      }
    } else {
      #pragma unroll
      for (int j = 0; j < 4; ++j){
        const float bval = biasS[kt*64 + j*16 + fr];
        #pragma unroll
        for (int r = 0; r < 4; ++r) sc[j][r] += bval;
      }
    }
    // online softmax with defer-max (T13, THR=8)
    float tmax[4];
    #pragma unroll
    for (int r = 0; r < 4; ++r)
      tmax[r] = fmaxf(fmaxf(sc[0][r], sc[1][r]), fmaxf(sc[2][r], sc[3][r]));
    #pragma unroll
    for (int o = 1; o < 16; o <<= 1)
      #pragma unroll
      for (int r = 0; r < 4; ++r)
        tmax[r] = fmaxf(tmax[r], __shfl_xor(tmax[r], o));
    bool grow = false;
    #pragma unroll
    for (int r = 0; r < 4; ++r) grow = grow || (tmax[r] > mrow[r] + 8.0f);
    if (__any(grow)){
      float fac[4];
      #pragma unroll
      for (int r = 0; r < 4; ++r){
        const float mn = fmaxf(mrow[r], tmax[r]);
        fac[r] = __expf(mrow[r] - mn);
        mrow[r] = mn;
        lrow[r] *= fac[r];
      }
      #pragma unroll
      for (int f = 0; f < 4; ++f)
        #pragma unroll
        for (int r = 0; r < 4; ++r) accO[f][r] *= fac[r];
    }
    float tsum[4] = {0.0f, 0.0f, 0.0f, 0.0f};
    #pragma unroll
    for (int j = 0; j < 4; ++j)
      #pragma unroll
      for (int r = 0; r < 4; ++r){
        const float p = __expf(sc[j][r] - mrow[r]);
        sc[j][r] = p; tsum[r] += p;
      }
    #pragma unroll
    for (int o = 1; o < 16; o <<= 1)
      #pragma unroll
      for (int r = 0; r < 4; ++r) tsum[r] += __shfl_xor(tsum[r], o);
    #pragma unroll
    for (int r = 0; r < 4; ++r) lrow[r] += tsum[r];

    // P -> wave-private LDS (chunk-swizzled), read back as A-frags
    #pragma unroll
    for (int j = 0; j < 4; ++j)
      #pragma unroll
      for (int r = 0; r < 4; ++r){
        const int row = kg*4 + r;
        const int col = j*16 + fr;
        Pw[row*64 + (((col >> 3) ^ (row & 7)) * 8) + (col & 7)] = f2bf(sc[j][r]);
      }
    bfrag8 ap[2];
    #pragma unroll
    for (int c2 = 0; c2 < 2; ++c2)
      ap[c2] = *(const bfrag8*)&Pw[fr*64 + (((c2*4 + kg) ^ (fr & 7)) * 8)];
    __builtin_amdgcn_s_setprio(1);
    #pragma unroll
    for (int f = 0; f < 4; ++f){
      accO[f] = __builtin_amdgcn_mfma_f32_16x16x32_bf16(ap[0], bv[f][0], accO[f], 0, 0, 0);
      accO[f] = __builtin_amdgcn_mfma_f32_16x16x32_bf16(ap[1], bv[f][1], accO[f], 0, 0, 0);
    }
    __builtin_amdgcn_s_setprio(0);
  }

  // epilogue: O/lrow via Pw bounce -> coalesced 16B stores
  #pragma unroll
  for (int f = 0; f < 4; ++f)
    #pragma unroll
    for (int r = 0; r < 4; ++r){
      const int row = kg*4 + r;
      const int col = f*16 + fr;
      Pw[(row*64 + col) ^ ((row & 7) << 3)] = f2bf(accO[f][r] / lrow[r]);
    }
  const int prow = lane >> 2, pch = lane & 3;
  const long orow = (long)(b*512 + qt*64 + wid*16 + prow) * 1024 + h*64;
  #pragma unroll
  for (int it2 = 0; it2 < 2; ++it2){
    const int ch2 = pch + it2*4;
    int4 w4 = *(const int4*)&Pw[(prow*64 + ch2*8) ^ ((prow & 7) << 3)];
    *(int4*)&O[orow + ch2*8] = w4;
  }
}

// ---- ALL 5 attentions in one launch, grid (8,64,5); z=0 self, z>=1 cross ----
__global__ __launch_bounds__(256, 3) void flash_all5(
    const u16* __restrict__ Qb5, const u16* __restrict__ Kb,
    const u16* __restrict__ Vtb, const u16* __restrict__ KVcl,
    const int* __restrict__ cmask, u16* __restrict__ O5)
{
  __shared__ __align__(16) u16 Ks[2][64*64];
  __shared__ __align__(16) u16 Vs[2][64*64];
  __shared__ __align__(16) u16 Ps[4*16*64];
  __shared__ float biasS[512];
  const int z = blockIdx.z;
  const int fid = blockIdx.y * 8 + blockIdx.x;
  const int lid = (fid & 7) * 64 + (fid >> 3);
  const int qt = lid & 7, bh = lid >> 3;
  constexpr long NB = (long)2048 * 1024;
  if (z == 0){
    flash_body<true>(Qb5, Kb, Vtb, nullptr, O5, qt, bh, Ks, Vs, Ps);
  } else {
    const int ci = z - 1;
    const int mode = (0x0312 >> (ci*4)) & 0xF;   // ci: 0->2, 1->1, 2->3, 3->0
    const int b = bh >> 4;
    const int tid = threadIdx.x;
    #pragma unroll
    for (int r = 0; r < 2; ++r){
      const int c = r * 256 + tid;
      biasS[c] = (cmask[b * 512 + c] != mode) ? 0.0f : -1e20f;
    }
    __syncthreads();
    flash_body<false>(Qb5 + (long)z * NB,
                      KVcl + (long)(ci*2) * NB, KVcl + (long)(ci*2 + 1) * NB,
                      biasS, O5 + (long)z * NB, qt, bh, Ks, Vs, Ps);
  }
}

// ---------------------------------------------------------------------------
#define MODE_F32   0
#define MODE_BF16  1
#define MODE_PROJ  6
#define MODE_F32B  7

__device__ __forceinline__ long qk_off(int gm, int gn){   // [b,h,t,d]
  return (((long)(gm >> 9) * HH + (gn >> 6)) * TT + (gm & (TT-1))) * DHH + (gn & (DHH-1));
}

// ---------------------------------------------------------------------------
// 8-phase 256x256 GEMM (guide's m201 template, plain HIP) for the KV
// precompute. Verified correct r25; ~neutral vs 128^2 at K=1024 (template's
// 1563 TF does NOT transfer at 16 K-tiles / 2 dispatch rounds) — kept.
// ---------------------------------------------------------------------------
__global__ __launch_bounds__(512, 2) void gemm256_kv(
    const u16* __restrict__ A, const u16* __restrict__ B,
    const float* __restrict__ bkb, const float* __restrict__ bvb,
    u16* __restrict__ Cb)
{
  __shared__ __align__(16) u16 lds[65536];     // 128 KB

  const int gx = gridDim.x, gy = gridDim.y;
  const int nwg = gx * gy * gridDim.z;
  const int fid = (blockIdx.z * gy + blockIdx.y) * gx + blockIdx.x;
  const int cpx = nwg >> 3;
  const int lid = (fid & 7) * cpx + (fid >> 3);
  const int bx = lid % gx;
  const int rem = lid / gx;
  const int by = rem % gy;
  const int z  = rem / gy;

  constexpr long NBA = (long)2048 * 1024;
  constexpr long D2C = (long)DD * DD;
  const int ci = z >> 2, ll = (z >> 1) & 1, isv = z & 1;
  const u16* Ab = A + (long)ci * NBA;
  const u16* Bb = B + (long)(ll*8 + ci*2 + isv) * D2C;
  const long cbase = (long)(ll*8 + ci*2 + isv) * NBA;

  const int tid = threadIdx.x, lane = tid & 63, w = tid >> 6;
  const int m0 = by * 256, n0 = bx * 256;
  const int wmh = w >> 2;                  // A half (M 128-range)
  const int wn  = w & 3;                   // 64-col group
  const int bhf = wn >> 1;                 // B half
  const int brow0 = (wn & 1) * 64;         // row base within B half
  const int fr = lane & 15, kg = lane >> 4;
  facc4 acc[8][4] = {};

  const int sr8 = (tid >> 3) & 7;
  const int sgc = ((tid & 7) ^ sr8) * 8;   // pre-swizzled global chunk

  auto stageA = [&](int buf, int h, int t){
    u16* d = lds + (buf*2 + h) * 8192 + tid * 8;
    #pragma unroll
    for (int p = 0; p < 2; ++p)
      gload16(Ab + (long)(m0 + h*128 + p*64 + (tid >> 3)) * DD + t*64 + sgc,
              d + p*4096);
  };
  auto stageB = [&](int buf, int h, int t){
    u16* d = lds + 32768 + (buf*2 + h) * 8192 + tid * 8;
    #pragma unroll
    for (int p = 0; p < 2; ++p)
      gload16(Bb + (long)(n0 + h*128 + p*64 + (tid >> 3)) * DD + t*64 + sgc,
              d + p*4096);
  };

  bfrag8 af[4][2], bf[4][2];
  auto readA = [&](int buf, int mg){
    const u16* Ah = lds + (buf*2 + wmh) * 8192;
    #pragma unroll
    for (int q = 0; q < 4; ++q){
      const int row = (mg*4 + q)*16 + fr;
      #pragma unroll
      for (int c2 = 0; c2 < 2; ++c2)
        af[q][c2] = *(const bfrag8*)&Ah[row*64 + (((c2*4 + kg) ^ (fr & 7)) * 8)];
    }
  };
  auto readB = [&](int buf, int ng){
    const u16* Bh = lds + 32768 + (buf*2 + bhf) * 8192;
    #pragma unroll
    for (int q = 0; q < 2; ++q){
      const int row = brow0 + (ng*2 + q)*16 + fr;
      #pragma unroll
      for (int c2 = 0; c2 < 2; ++c2)
        bf[ng*2 + q][c2] = *(const bfrag8*)&Bh[row*64 + (((c2*4 + kg) ^ (fr & 7)) * 8)];
    }
  };
  auto mmaQ = [&](int mg, int ng){
    __builtin_amdgcn_s_setprio(1);
    #pragma unroll
    for (int q = 0; q < 4; ++q)
      #pragma unroll
      for (int r2 = 0; r2 < 2; ++r2){
        const int i = mg*4 + q, j = ng*2 + r2;
        acc[i][j] = __builtin_amdgcn_mfma_f32_16x16x32_bf16(af[q][0], bf[j][0], acc[i][j], 0, 0, 0);
        acc[i][j] = __builtin_amdgcn_mfma_f32_16x16x32_bf16(af[q][1], bf[j][1], acc[i][j], 0, 0, 0);
      }
    __builtin_amdgcn_s_setprio(0);
  };

  // prologue: tiles 0 (buf0) and 1 (buf1) fully staged
  stageB(0,0,0); stageB(0,1,0); stageA(0,0,0); stageA(0,1,0);
  stageB(1,0,1); stageB(1,1,1); stageA(1,0,1); stageA(1,1,1);
  vwait<8>();                              // buf0[0] landed
  __builtin_amdgcn_s_barrier();

  for (int J = 0; J < 8; ++J){
    const int t2 = 2*J + 2, t3 = 2*J + 3;
    const bool pf = (J < 7);
    // ph1: tile a=(2J) quadrant (0,0)
    readA(0, 0); readB(0, 0);
    __builtin_amdgcn_sched_barrier(0);
    __builtin_amdgcn_s_barrier();
    mmaQ(0, 0);
    __builtin_amdgcn_s_barrier();
    // ph2: (0,1)
    readB(0, 1);
    __builtin_amdgcn_sched_barrier(0);
    __builtin_amdgcn_s_barrier();
    mmaQ(0, 1);
    __builtin_amdgcn_s_barrier();
    // ph3: (1,0); stage buf0.B0[t2]
    readA(0, 1);
    if (pf) stageB(0, 0, t2);
    __builtin_amdgcn_sched_barrier(0);
    __builtin_amdgcn_s_barrier();
    mmaQ(1, 0);
    __builtin_amdgcn_s_barrier();
    // ph4: (1,1); stage buf0.B1[t2]; counted wait -> buf1[b] landed
    if (pf){ stageB(0, 1, t2); vwait<4>(); }
    else vwait<0>();
    __builtin_amdgcn_s_barrier();
    mmaQ(1, 1);
    __builtin_amdgcn_s_barrier();
    // ph5: tile b=(2J+1) quadrant (0,0); stage buf0.A0+A1[t2]
    readA(1, 0); readB(1, 0);
    if (pf){ stageA(0, 0, t2); stageA(0, 1, t2); }
    __builtin_amdgcn_sched_barrier(0);
    __builtin_amdgcn_s_barrier();
    mmaQ(0, 0);
    __builtin_amdgcn_s_barrier();
    // ph6: (0,1)
    readB(1, 1);
    __builtin_amdgcn_sched_barrier(0);
    __builtin_amdgcn_s_barrier();
    mmaQ(0, 1);
    __builtin_amdgcn_s_barrier();
    // ph7: (1,0); stage buf1.B0[t3]
    readA(1, 1);
    if (pf) stageB(1, 0, t3);
    __builtin_amdgcn_sched_barrier(0);
    __builtin_amdgcn_s_barrier();
    mmaQ(1, 0);
    __builtin_amdgcn_s_barrier();
    // ph8: (1,1); stage buf1.{B1,A0,A1}[t3]; counted wait -> buf0[t2] landed
    if (pf){ stageB(1, 1, t3); stageA(1, 0, t3); stageA(1, 1, t3); }
    vwait<6>();
    __builtin_amdgcn_s_barrier();
    mmaQ(1, 1);
    __builtin_amdgcn_s_barrier();
  }
  __syncthreads();

  // ---- epilogue: bounce through LDS (reuses full 128KB) ----
  u16* S = lds;
  if (isv){                                // V: transpose to [b,h,d,t]
    const float* vb = bvb + (long)(ll*5 + ci + 1) * DD;
    #pragma unroll
    for (int j = 0; j < 4; ++j){
      const int nl = wn*64 + j*16 + fr;
      const float bvv = vb[n0 + nl];
      #pragma unroll
      for (int i = 0; i < 8; ++i)
        #pragma unroll
        for (int rr = 0; rr < 4; ++rr){
          const int ml = wmh*128 + i*16 + kg*4 + rr;
          S[(nl*256 + ml) ^ ((nl & 7) << 3)] = f2bf(acc[i][j][rr] + bvv);
        }
    }
    __syncthreads();
    const int n = tid >> 1;                // 0..255
    const int mh = (tid & 1) * 128;
    const long rowoff = (((long)(m0 >> 9) * HH + ((n0 + n) >> 6)) * DHH
                         + ((n0 + n) & 63)) * TT + (m0 & 511) + mh;
    u16* vdst = Cb + cbase;
    #pragma unroll
    for (int c = 0; c < 16; ++c){
      int4 w4 = *(const int4*)&S[(n*256 + mh + c*8) ^ ((n & 7) << 3)];
      *(int4*)&vdst[rowoff + c*8] = w4;
    }
  } else {                                 // K: row-major [b,h,t,d]
    const float* bp = bkb + (long)(ll*5 + ci + 1) * DD;
    #pragma unroll
    for (int i = 0; i < 8; ++i)
      #pragma unroll
      for (int j = 0; j < 4; ++j){
        const int nl = wn*64 + j*16 + fr;
        const float bvv = bp[n0 + nl];
        #pragma unroll
        for (int rr = 0; rr < 4; ++rr){
          const int ml = wmh*128 + i*16 + kg*4 + rr;
          S[(ml*256 + nl) ^ ((ml & 7) << 3)] = f2bf(acc[i][j][rr] + bvv);
        }
      }
    __syncthreads();
    #pragma unroll
    for (int it = 0; it < 16; ++it){
      const int idx = it * 512 + tid;
      const int row = idx >> 5, ch = idx & 31;
      int4 w4 = *(const int4*)&S[(row*256 + ch*8) ^ ((row & 7) << 3)];
      *(int4*)&Cb[cbase + qk_off(m0 + row, n0 + ch*8)] = w4;
    }
  }
}

// ---------------------------------------------------------------------------
// 256-thread bf16 MFMA GEMM, BK=64, counted-vmcnt pipeline, XCD swizzle.
// NBUF=3 for 64x64 tiles; 2 otherwise. MINW: min waves/EU for launch_bounds
// (64^2 NBUF=3 = 48KB LDS -> 3 blocks/CU fit; 128^2 = 64KB -> 2 max).
// ---------------------------------------------------------------------------
template<int BM, int BN, int MODE, int MINW = 2>
__global__ __launch_bounds__(256, MINW) void gemm_k(
    const u16* __restrict__ A, const u16* __restrict__ B,
    const float* __restrict__ bias0, const float* __restrict__ bias1,
    const float* __restrict__ bias2,
    float* __restrict__ Cf, u16* __restrict__ Cb0, u16* __restrict__ Cb1,
    u16* __restrict__ Cb2, const u16* __restrict__ resb,
    int K, int lda, int ldb, int ldc,
    int relu, float alpha)
{
  constexpr int BK = 64;
  constexpr int NBUF = (BM == 64 && BN == 64) ? 3 : 2;
  constexpr int ASZ = BM * BK, BSZ = BN * BK;
  __shared__ __align__(16) u16 As[NBUF * ASZ];
  __shared__ __align__(16) u16 Bs[NBUF * BSZ];

  const int gx = gridDim.x, gy = gridDim.y;
  const int nwg = gx * gy * gridDim.z;
  const int fid = (blockIdx.z * gy + blockIdx.y) * gx + blockIdx.x;
  const int cpx = nwg >> 3;
  const int lid = (fid & 7) * cpx + (fid >> 3);
  const int bx = lid % gx;
  const int rem = lid / gx;
  const int by = rem % gy;
  const int z  = rem / gy;

  const u16* Ab;
  const u16* Bb;
  long cbase;
  constexpr long NBA = (long)2048 * 1024;
  constexpr long D2C = (long)DD * DD;
  if constexpr (MODE == MODE_F32B){
    Ab = A + (long)z * NBA;
    Bb = B + (long)z * D2C;
    cbase = (long)z * NBA;
  } else {
    Ab = A; Bb = B; cbase = 0;
  }
  const int tid = threadIdx.x, lane = tid & 63, wid = tid >> 6;
  const int m0 = by * BM, n0 = bx * BN;
  constexpr int TMW = BM / 2, TNW = BN / 2;           // 2x2 wave grid
  constexpr int FM = TMW / 16, FN = TNW / 16;
  const int wm = (wid >> 1) * TMW, wn = (wid & 1) * TNW;
  const int fr = lane & 15, kg = lane >> 4;
  facc4 acc[FM][FN] = {};

  const int srow = tid >> 3;
  const int gcol = (((tid & 7) ^ (srow & 7)) * 8);
  constexpr int AP = BM / 32, BP = BN / 32;
  constexpr int LPS = AP + BP;

  auto stage = [&](int buf, int k0){
    u16* Ad = As + buf * ASZ + wid * 512;
    u16* Bd = Bs + buf * BSZ + wid * 512;
    #pragma unroll
    for (int p = 0; p < AP; ++p)
      gload16(Ab + (long)(m0 + p*32 + srow) * lda + (k0 + gcol), Ad + p*2048);
    #pragma unroll
    for (int p = 0; p < BP; ++p)
      gload16(Bb + (long)(n0 + p*32 + srow) * ldb + (k0 + gcol), Bd + p*2048);
  };

  const int nsteps = K / BK;
  stage(0, 0);
  if constexpr (NBUF == 3){
    if (nsteps > 1) stage(1, BK);
    if (nsteps > 2) stage(2, 2*BK);
    if (nsteps > 2) vwait<2*LPS>();
    else if (nsteps > 1) vwait<LPS>();
    else vwait<0>();
  } else {
    if (nsteps > 1){ stage(1, BK); vwait<LPS>(); }
    else vwait<0>();
  }
  __builtin_amdgcn_s_barrier();

  int cur = 0;
  for (int s = 0; s < nsteps; ++s){
    const u16* Ar = As + cur * ASZ;
    const u16* Br = Bs + cur * BSZ;
    bfrag8 af[FM][2], bfv[FN][2];
    #pragma unroll
    for (int i = 0; i < FM; ++i)
      #pragma unroll
      for (int c2 = 0; c2 < 2; ++c2)
        af[i][c2] = *(const bfrag8*)&Ar[(wm + i*16 + fr) * 64 + (((c2*4 + kg) ^ (fr & 7)) * 8)];
    #pragma unroll
    for (int j = 0; j < FN; ++j)
      #pragma unroll
      for (int c2 = 0; c2 < 2; ++c2)
        bfv[j][c2] = *(const bfrag8*)&Br[(wn + j*16 + fr) * 64 + (((c2*4 + kg) ^ (fr & 7)) * 8)];
    __builtin_amdgcn_sched_barrier(0);
    __builtin_amdgcn_s_barrier();
    if constexpr (NBUF == 3){
      if (s + 3 < nsteps){ stage(cur, (s + 3) * BK); vwait<2*LPS>(); }
      else if (s + 2 < nsteps) vwait<LPS>();
      else if (s + 1 < nsteps) vwait<0>();
    } else {
      if (s + 2 < nsteps){ stage(cur, (s + 2) * BK); vwait<LPS>(); }
      else if (s + 1 < nsteps) vwait<0>();
    }
    __builtin_amdgcn_s_barrier();
    #pragma unroll
    for (int i = 0; i < FM; ++i)
      #pragma unroll
      for (int j = 0; j < FN; ++j){
        acc[i][j] = __builtin_amdgcn_mfma_f32_16x16x32_bf16(af[i][0], bfv[j][0], acc[i][j], 0, 0, 0);
        acc[i][j] = __builtin_amdgcn_mfma_f32_16x16x32_bf16(af[i][1], bfv[j][1], acc[i][j], 0, 0, 0);
      }
    cur = (cur == NBUF - 1) ? 0 : cur + 1;
  }

  // ---- V^T output path (PROJ V_self section): LDS transpose bounce ----
  if constexpr (MODE == MODE_PROJ){
    if ((n0 >> 10) == 6){
      const float* vb = bias2;
      u16* vdst = Cb2;
      const int n0e = n0 - 6144;
      u16* S = Bs;
      #pragma unroll
      for (int j = 0; j < FN; ++j){
        const int nl = wn + j*16 + fr;
        const float bvv = vb[n0e + nl];
        #pragma unroll
        for (int i = 0; i < FM; ++i)
          #pragma unroll
          for (int rr = 0; rr < 4; ++rr){
            const int ml = wm + i*16 + kg*4 + rr;
            S[(nl*BM + ml) ^ ((nl & 7) << 3)] = f2bf(acc[i][j][rr] + bvv);
          }
      }
      __syncthreads();
      constexpr int TPR = 256 / BN;
      constexpr int CPT = BM / (8 * TPR);
      const int n = tid / TPR;
      const int mh = (tid % TPR) * (BM / TPR);
      const long rowoff = (((long)(m0 >> 9) * HH + ((n0e + n) >> 6)) * DHH
                           + ((n0e + n) & 63)) * TT + (m0 & 511) + mh;
      #pragma unroll
      for (int c = 0; c < CPT; ++c){
        int4 w4 = *(const int4*)&S[(n*BM + mh + c*8) ^ ((n & 7) << 3)];
        *(int4*)&vdst[rowoff + c*8] = w4;
      }
      return;
    }
  }

  // ---- bf16 row-major bounce (MODE_BF16 / PROJ Q,K) ----
  if constexpr (MODE == MODE_BF16 || MODE == MODE_PROJ){
    u16* S = As;                 // NBUF*ASZ u16 >= BM*BN u16 for all configs
    const float* bp = bias0;
    float sc2 = alpha;
    u16* dst = Cb0;
    int nb = 0;
    constexpr long NBA2 = (long)2048 * 1024;
    if constexpr (MODE == MODE_PROJ){
      const int sect = n0 >> 10;           // 0..5 here (128 | 1024 -> no straddle)
      nb = n0 & 1023;
      if (sect <= 4){ bp = bias0 + (long)sect * DD; sc2 = 0.125f; dst = Cb0 + (long)sect * NBA2; }
      else          { bp = bias1; sc2 = 1.0f; dst = Cb1; }
    }
    #pragma unroll
    for (int i = 0; i < FM; ++i)
      #pragma unroll
      for (int j = 0; j < FN; ++j){
        const int nl = wn + j*16 + fr;
        float bvv;
        if constexpr (MODE == MODE_PROJ) bvv = bp[nb + nl];
        else bvv = bp ? bp[n0 + nl] : 0.0f;
        #pragma unroll
        for (int rr = 0; rr < 4; ++rr){
          const int ml = wm + i*16 + kg*4 + rr;
          float v = (acc[i][j][rr] + bvv) * sc2;
          if (relu) v = fmaxf(v, 0.0f);
          S[(ml*BN + nl) ^ ((ml & 7) << 3)] = f2bf(v);
        }
      }
    __syncthreads();
    constexpr int CPR = BN / 8;                 // 16B chunks per row
    constexpr int NIT = (BM * CPR) / 256;
    #pragma unroll
    for (int it = 0; it < NIT; ++it){
      const int idx = it * 256 + tid;
      const int row = idx / CPR, ch = idx % CPR;
      int4 w4 = *(const int4*)&S[(row*BN + ch*8) ^ ((row & 7) << 3)];
      const int gm = m0 + row;
      long off;
      if constexpr (MODE == MODE_BF16) off = cbase + (long)gm * ldc + (n0 + ch*8);
      else off = qk_off(gm, nb + ch*8);
      *(int4*)&dst[off] = w4;
    }
    return;
  }

  // Epilogue (MODE_F32 / MODE_F32B). C/D layout: col = fr, row = kg*4 + rr.
  {
    const float* bp0 = bias0;
    if constexpr (MODE == MODE_F32B) bp0 = bias0 + (long)z * DD;
    #pragma unroll
    for (int i = 0; i < FM; ++i){
      #pragma unroll
      for (int j = 0; j < FN; ++j){
        const int gn = n0 + wn + j*16 + fr;
        #pragma unroll
        for (int rr = 0; rr < 4; ++rr){
          const int gm = m0 + wm + i*16 + kg*4 + rr;
          float v = acc[i][j][rr];
          v = (v + (bp0 ? bp0[gn] : 0.0f)) * alpha;
          if (relu) v = fmaxf(v, 0.0f);
          const long off = cbase + (long)gm * ldc + gn;
          if constexpr (MODE == MODE_F32){
            if (resb) v += bf2f(resb[off]);        // fused bf16 residual
          }
          Cf[off] = v;
        }
      }
    }
  }
}

// ---------------------------------------------------------------------------
extern "C" void kernel_launch(void* const* d_in, const int* in_sizes, int n_in,
                              void* d_out, int out_size, void* d_ws, size_t ws_size,
                              hipStream_t stream)
{
  (void)in_sizes; (void)n_in; (void)out_size; (void)ws_size;
  const float* emb   = (const float*)d_in[0];
  const int*   pvec  = (const int*)d_in[1];
  const float* g_enc = (const float*)d_in[2];
  const float* g_con = (const float*)d_in[3];
  const float* g_db  = (const float*)d_in[4];
  const float* g_usr = (const float*)d_in[5];
  const int*   cmask = (const int*)d_in[6];
  const float* pose  = (const float*)d_in[7];
  const float* Wq = (const float*)d_in[8];
  const float* bq = (const float*)d_in[9];
  const float* Wk = (const float*)d_in[10];
  const float* bk = (const float*)d_in[11];
  const float* Wv = (const float*)d_in[12];
  const float* bv = (const float*)d_in[13];
  const float* Wo = (const float*)d_in[14];
  const float* bo = (const float*)d_in[15];
  const float* W1 = (const float*)d_in[16];
  const float* b1 = (const float*)d_in[17];
  const float* W2 = (const float*)d_in[18];
  const float* b2 = (const float*)d_in[19];
  float* out = (float*)d_out;

  const size_t NTOK = (size_t)BB * TT;   // 2048
  const long D2 = (long)DD * DD;

  char* wp = (char*)d_ws;
  auto alloc = [&](size_t bytes) -> char* {
    char* p = wp;
    wp += (bytes + 255) & ~(size_t)255;
    return p;
  };
  // NOTE: the first 5 arrays' order/offsets are hard-coded in prep_all.
  u16*   WprojT = (u16*) alloc(sizeof(u16) * 2 * 7 * D2);   // [l][7 slots]
  u16*   WkvC   = (u16*) alloc(sizeof(u16) * 2 * 4 * 2 * D2);
  u16*   WoT    = (u16*) alloc(sizeof(u16) * 10 * D2);
  u16*   W1T    = (u16*) alloc(sizeof(u16) * 2 * DD * FF);
  u16*   W2T    = (u16*) alloc(sizeof(u16) * 2 * DD * FF);
  // kvb0..3 MUST stay contiguous: gemm256_kv indexes them as [4][NTOK][DD]
  u16*   kvb0  = (u16*)  alloc(sizeof(u16) * NTOK * DD);
  u16*   kvb1  = (u16*)  alloc(sizeof(u16) * NTOK * DD);
  u16*   kvb2  = (u16*)  alloc(sizeof(u16) * NTOK * DD);
  u16*   kvb3  = (u16*)  alloc(sizeof(u16) * NTOK * DD);
  u16*   KVc   = (u16*)  alloc(sizeof(u16) * 16 * NTOK * DD);
  u16*   xb    = (u16*)  alloc(sizeof(u16) * NTOK * DD);
  u16*   Qb5   = (u16*)  alloc(sizeof(u16) * 5 * NTOK * DD);
  u16*   Kb    = (u16*)  alloc(sizeof(u16) * NTOK * DD);
  u16*   Vtb   = (u16*)  alloc(sizeof(u16) * NTOK * DD);
  u16*   attnb5= (u16*)  alloc(sizeof(u16) * 5 * NTOK * DD);
  float* oproj5= (float*)alloc(sizeof(float) * 5 * NTOK * DD);
  float* obuf  = (float*)alloc(sizeof(float) * NTOK * DD);
  u16*   hb    = (u16*)  alloc(sizeof(u16) * NTOK * FF);

  // ---- ONE prep launch: transposes + kv converts + embed/LN ----
  prep_all<<<24576, 256, 0, stream>>>(
      Wq, Wk, Wv, Wo, W1, W2, g_db, g_con, g_usr, g_enc,
      (u16*)d_ws, kvb0, kvb1, kvb2, kvb3,
      emb, pvec, pose, xb);

  // ---- all cross-attention K/V: 8-phase 256^2 template, 512 blocks ----
  const long NB = (long)NTOK * DD;
  gemm256_kv<<<dim3(4,8,16), 512, 0, stream>>>(kvb0, WkvC, bk, bv, KVc);

  for (int l = 0; l < 2; ++l){
    // ---- batched projections: [Q x5 | K_self | V_self], N = 7168 ----
    gemm_k<128,128,MODE_PROJ><<<dim3(56,16,1), 256, 0, stream>>>(
      xb, WprojT + (long)l*7*D2,
      bq + (size_t)l*5*DD, bk + (size_t)l*5*DD, bv + (size_t)l*5*DD,
      nullptr, Qb5, Kb, Vtb, nullptr,
      DD, DD, DD, 0, 0, 1.0f);

    // ALL 5 attentions (self causal + 4 cross) in one launch
    flash_all5<<<dim3(8,64,5), 256, 0, stream>>>(
        Qb5, Kb, Vtb, KVc + (long)l*8*NB, cmask, attnb5);

    // ALL 5 O-projections batched (z = i), f32 out, 128x128 tiles
    gemm_k<128,128,MODE_F32B><<<dim3(8,16,5), 256, 0, stream>>>(
      attnb5, WoT + (long)l*5*D2,
      bo + (size_t)l*5*DD, nullptr, nullptr,
      oproj5, nullptr, nullptr, nullptr, nullptr,
      DD, DD, DD, DD, 0, 1.0f);

    // chained residual+LN (one launch, f32 registers across 5 steps)
    ln_chain5<<<(int)NTOK, 256, 0, stream>>>(oproj5, xb);

    // FFN
    gemm_k<128,128,MODE_BF16><<<dim3(32,16,1), 256, 0, stream>>>(
      xb, W1T + (size_t)l*DD*FF,
      b1 + (size_t)l*FF, nullptr, nullptr,
      nullptr, hb, nullptr, nullptr, nullptr,
      DD, DD, DD, FF, 1, 1.0f);
    // FFN2 at 3 blocks/CU (48KB LDS x3 = 144 <= 160; VGPR-light kernel)
    gemm_k<64,64,MODE_F32,3><<<dim3(16,32,1), 256, 0, stream>>>(
      hb, W2T + (size_t)l*DD*FF,
      b2 + (size_t)l*DD, nullptr, nullptr,
      obuf, nullptr, nullptr, nullptr, xb,
      FF, FF, FF, DD, 0, 1.0f);
    float* yf = (l == 1) ? out : nullptr;
    ln_kernel<<<(int)NTOK, 256, 0, stream>>>(obuf, yf, (l == 1) ? nullptr : xb);
  }
}